// Round 3
// baseline (1473.334 us; speedup 1.0000x reference)
//
#include <hip/hip_runtime.h>
#include <cstdint>
#include <cstddef>

// ---------------------------------------------------------------------------
// RNNAttentionModel: embed -> 2-layer tanh RNN scan (MFMA-batched) ->
// causal self-attention (bf16 MFMA GEMMs) -> concat -> FC(55)
// B=64 T=1024 E=64 H=128 V=55
// ---------------------------------------------------------------------------

typedef __attribute__((ext_vector_type(8))) short short8;   // 8 x bf16 frag
typedef __attribute__((ext_vector_type(4))) float f32x4;

__device__ __forceinline__ float bf2f(unsigned short u) {
    union { unsigned int i; float f; } c; c.i = ((unsigned int)u) << 16; return c.f;
}
__device__ __forceinline__ unsigned short f2bf(float f) {
    union { float f; unsigned int i; } c; c.f = f;
    unsigned int u = c.i;
    u += 0x7fffu + ((u >> 16) & 1u);   // RNE
    return (unsigned short)(u >> 16);
}
__device__ __forceinline__ float fast_tanh(float x) {
    float e = __expf(2.0f * x);
    return 1.0f - 2.0f / (e + 1.0f);
}
// Raw workgroup barrier: waits LDS ops only; global loads/stores stay in
// flight (avoids the vmcnt(0) drain __syncthreads() would emit every step).
__device__ __forceinline__ void bar_lds() {
    asm volatile("s_waitcnt lgkmcnt(0)\n\ts_barrier" ::: "memory");
}

// ---------------------------------------------------------------------------
// K0a: WE[v][i] = w_ih0[i,:] . emb[v,:] + b_ih0[i] + b_hh0[i]   (55 x 128)
// ---------------------------------------------------------------------------
__global__ __launch_bounds__(128)
void k_we(const float* __restrict__ emb, const float* __restrict__ w_ih0,
          const float* __restrict__ b_ih0, const float* __restrict__ b_hh0,
          float* __restrict__ WE)
{
    __shared__ float ev[64];
    const int i = threadIdx.x;
    const int v = blockIdx.x;
    if (i < 64) ev[i] = emb[v * 64 + i];
    __syncthreads();
    float s = b_ih0[i] + b_hh0[i];
    const float* wr = w_ih0 + i * 64;
#pragma unroll
    for (int k = 0; k < 64; ++k) s += wr[k] * ev[k];
    WE[v * 128 + i] = s;
}

// ---------------------------------------------------------------------------
// K0b: WEg[b][t][:] = WE[x[b][t]][:]   (pre-gathered layer-0 pre-activation)
// ---------------------------------------------------------------------------
__global__ __launch_bounds__(256)
void k_weg(const int* __restrict__ x, const float* __restrict__ WE,
           float* __restrict__ WEg)
{
    __shared__ int xv[32];
    const int tid = threadIdx.x;
    const int b   = blockIdx.y;
    const int t0  = blockIdx.x * 32;
    if (tid < 32) xv[tid] = x[b * 1024 + t0 + tid];
    __syncthreads();
#pragma unroll
    for (int it = 0; it < 4; ++it) {
        int tt = it * 8 + (tid >> 5);
        int c4 = tid & 31;
        float4 v = ((const float4*)(WE + xv[tt] * 128))[c4];
        ((float4*)(WEg + ((size_t)b * 1024 + t0 + tt) * 128))[c4] = v;
    }
}

// ---------------------------------------------------------------------------
// K1: MFMA-batched RNN scan. 4 blocks x 16 batches, 512 threads (8 waves).
// Wave w owns M-tile rows 16w..16w+15 of Whh0 / Wih1 / Whh1 as stationary
// bf16 A-frags (48 VGPRs). h-state (bf16) lives in LDS as B-frag layout
// [batch][k] (stride 136 shorts, conflict-free), double-buffered -> ONE
// barrier per step. Per step/wave: 8 ds_read_b128 + 12 MFMA + tanh.
// ---------------------------------------------------------------------------
__global__ __launch_bounds__(512, 1)
void k_scan3(const float* __restrict__ WEg,
             const float* __restrict__ w_hh0,
             const float* __restrict__ w_ih1, const float* __restrict__ b_ih1,
             const float* __restrict__ w_hh1, const float* __restrict__ b_hh1,
             unsigned short* __restrict__ outs_bf)
{
    const int tid   = threadIdx.x;
    const int w     = tid >> 6;          // wave 0..7 -> rows 16w..16w+15
    const int lane  = tid & 63;
    const int quad  = lane >> 4;
    const int n     = lane & 15;         // batch col (= A-row-in-tile index)
    const int bbase = blockIdx.x * 16;

    __shared__ __align__(16) unsigned short h0buf[2][16][136];
    __shared__ __align__(16) unsigned short h1buf[2][16][136];
    __shared__ __align__(16) unsigned short obuf[8][16][128];

    // ---- stationary A fragments (bf16): lane holds A[m=n][k=32ks+8q+j] ----
    short8 a0[4], a1[4], a2[4];
    {
        const size_t mrow = (size_t)(w * 16 + n) * 128;
#pragma unroll
        for (int ks = 0; ks < 4; ++ks) {
            const int ko = ks * 32 + quad * 8;
            const float4* p0 = (const float4*)(w_hh0 + mrow + ko);
            const float4* p1 = (const float4*)(w_ih1 + mrow + ko);
            const float4* p2 = (const float4*)(w_hh1 + mrow + ko);
            float4 f0 = p0[0], f1 = p0[1];
            short8 r;
            r[0]=(short)f2bf(f0.x); r[1]=(short)f2bf(f0.y);
            r[2]=(short)f2bf(f0.z); r[3]=(short)f2bf(f0.w);
            r[4]=(short)f2bf(f1.x); r[5]=(short)f2bf(f1.y);
            r[6]=(short)f2bf(f1.z); r[7]=(short)f2bf(f1.w);
            a0[ks] = r;
            f0 = p1[0]; f1 = p1[1];
            r[0]=(short)f2bf(f0.x); r[1]=(short)f2bf(f0.y);
            r[2]=(short)f2bf(f0.z); r[3]=(short)f2bf(f0.w);
            r[4]=(short)f2bf(f1.x); r[5]=(short)f2bf(f1.y);
            r[6]=(short)f2bf(f1.z); r[7]=(short)f2bf(f1.w);
            a1[ks] = r;
            f0 = p2[0]; f1 = p2[1];
            r[0]=(short)f2bf(f0.x); r[1]=(short)f2bf(f0.y);
            r[2]=(short)f2bf(f0.z); r[3]=(short)f2bf(f0.w);
            r[4]=(short)f2bf(f1.x); r[5]=(short)f2bf(f1.y);
            r[6]=(short)f2bf(f1.z); r[7]=(short)f2bf(f1.w);
            a2[ks] = r;
        }
    }
    // layer-1 bias for this lane's C rows (quad*4+reg within tile)
    float b1v[4];
#pragma unroll
    for (int r = 0; r < 4; ++r) {
        int row = w * 16 + quad * 4 + r;
        b1v[r] = b_ih1[row] + b_hh1[row];
    }

    // ---- prologue: h0(0) = tanh(WEg[b][0]); h1(-1) = 0; weg = WEg[b][1] ----
    const size_t wegBase = ((size_t)(bbase + n)) * 1024 * 128 + (w * 16 + quad * 4);
    {
        unsigned int* z = (unsigned int*)&h1buf[0][0][0];
        for (int i2 = tid; i2 < 16 * 136 / 2; i2 += 512) z[i2] = 0u;
        float4 w0 = *(const float4*)(WEg + wegBase);          // t = 0
        float h00[4];
        h00[0]=fast_tanh(w0.x); h00[1]=fast_tanh(w0.y);
        h00[2]=fast_tanh(w0.z); h00[3]=fast_tanh(w0.w);
        unsigned int lo = f2bf(h00[0]) | ((unsigned int)f2bf(h00[1]) << 16);
        unsigned int hi = f2bf(h00[2]) | ((unsigned int)f2bf(h00[3]) << 16);
        *(uint2*)&h0buf[0][n][w * 16 + quad * 4] = make_uint2(lo, hi);
    }
    float4 weg = *(const float4*)(WEg + wegBase + 128);       // t = 1
    __syncthreads();

    for (int t = 0; t < 1024; ++t) {
        const int p = t & 1;
        // ---- B-fragments: h0(t), h1(t-1) ----
        const unsigned short* h0p = &h0buf[p][n][quad * 8];
        const unsigned short* h1p = &h1buf[p][n][quad * 8];
        short8 bh0[4], bh1[4];
#pragma unroll
        for (int ks = 0; ks < 4; ++ks) {
            bh0[ks] = *(const short8*)(h0p + ks * 32);
            bh1[ks] = *(const short8*)(h1p + ks * 32);
        }
        f32x4 c0  = (f32x4){0.f,0.f,0.f,0.f};
        f32x4 c1a = (f32x4){0.f,0.f,0.f,0.f};
        f32x4 c1b = (f32x4){0.f,0.f,0.f,0.f};
#pragma unroll
        for (int ks = 0; ks < 4; ++ks) {
            c0  = __builtin_amdgcn_mfma_f32_16x16x32_bf16(a0[ks], bh0[ks], c0, 0,0,0);
            c1a = __builtin_amdgcn_mfma_f32_16x16x32_bf16(a1[ks], bh0[ks], c1a,0,0,0);
            c1b = __builtin_amdgcn_mfma_f32_16x16x32_bf16(a2[ks], bh1[ks], c1b,0,0,0);
        }
        // ---- h0(t+1) = tanh(c0 + WEg[t+1]) ----
        float h0n[4], h1n[4];
        h0n[0] = fast_tanh(c0[0] + weg.x);
        h0n[1] = fast_tanh(c0[1] + weg.y);
        h0n[2] = fast_tanh(c0[2] + weg.z);
        h0n[3] = fast_tanh(c0[3] + weg.w);
        if (t + 2 < 1024)
            weg = *(const float4*)(WEg + wegBase + (size_t)(t + 2) * 128);
        // ---- h1(t) = tanh(c1a + c1b + b1) ----
        h1n[0] = fast_tanh(c1a[0] + c1b[0] + b1v[0]);
        h1n[1] = fast_tanh(c1a[1] + c1b[1] + b1v[1]);
        h1n[2] = fast_tanh(c1a[2] + c1b[2] + b1v[2]);
        h1n[3] = fast_tanh(c1a[3] + c1b[3] + b1v[3]);

        const int rowo = w * 16 + quad * 4;
        {
            unsigned int lo = f2bf(h0n[0]) | ((unsigned int)f2bf(h0n[1]) << 16);
            unsigned int hi = f2bf(h0n[2]) | ((unsigned int)f2bf(h0n[3]) << 16);
            *(uint2*)&h0buf[p ^ 1][n][rowo] = make_uint2(lo, hi);
            lo = f2bf(h1n[0]) | ((unsigned int)f2bf(h1n[1]) << 16);
            hi = f2bf(h1n[2]) | ((unsigned int)f2bf(h1n[3]) << 16);
            *(uint2*)&h1buf[p ^ 1][n][rowo] = make_uint2(lo, hi);
            *(uint2*)&obuf[t & 7][n][rowo] = make_uint2(lo, hi);
        }
        bar_lds();
        if ((t & 7) == 7) {
            // flush obuf (h1(t-7..t)) -> global; extra barrier protects slot 0
            const uint4* src = (const uint4*)&obuf[0][0][0];
#pragma unroll
            for (int j = 0; j < 4; ++j) {
                int i4 = tid + j * 512;            // uint4 index, 2048 total
                uint4 v = src[i4];
                int hh = (i4 & 15) * 8;
                int nn = (i4 >> 4) & 15;
                int ss = i4 >> 8;
                *(uint4*)(outs_bf + ((size_t)(bbase + nn)) * 131072 +
                          (size_t)(t - 7 + ss) * 128 + hh) = v;
            }
            bar_lds();
        }
    }
}

// ---------------------------------------------------------------------------
// K2: outs [b][t][h] -> outsT [b][h][t]  (LDS tile transpose)
// ---------------------------------------------------------------------------
__global__ __launch_bounds__(256)
void k_transpose(const unsigned short* __restrict__ outs_bf,
                 unsigned short* __restrict__ outsT)
{
    __shared__ unsigned short lt[128][130];
    const int tid = threadIdx.x;
    const int t0  = blockIdx.x * 128;
    const int b   = blockIdx.y;
    const unsigned int* src =
        (const unsigned int*)(outs_bf + ((size_t)b * 1024 + t0) * 128);
    for (int idx = tid; idx < 8192; idx += 256) {
        int tr = idx >> 6, h2 = idx & 63;
        unsigned int v = src[tr * 64 + h2];
        lt[tr][h2 * 2]     = (unsigned short)(v & 0xffffu);
        lt[tr][h2 * 2 + 1] = (unsigned short)(v >> 16);
    }
    __syncthreads();
    unsigned int* dst = (unsigned int*)(outsT + (size_t)b * 128 * 1024);
    for (int idx = tid; idx < 8192; idx += 256) {
        int h = idx >> 6, t2 = idx & 63;
        unsigned int v = (unsigned int)lt[t2 * 2][h] |
                         ((unsigned int)lt[t2 * 2 + 1][h] << 16);
        dst[h * 512 + (t0 >> 1) + t2] = v;
    }
}

// ---------------------------------------------------------------------------
// MFMA GEMM core conventions (16x16x32 bf16):
//   A frag: lane holds A[m=16*tile+(lane&15)][k = 8*(lane>>4) .. +7]
//   B frag: lane holds B[k][n] gathered as Brow[n=16*tile+(lane&15)][same k]
//   C/D   : col = lane&15, row = 4*(lane>>4) + reg
// LDS layout [row][k], 16B chunks XOR-swizzled: phys_k8 = k8 ^ (row & mask)
// ---------------------------------------------------------------------------

// K3: Q = outs @ attn_w.T + attn_b   (M = B*T, N = K = 128, one LDS pass)
__global__ __launch_bounds__(256, 2)
void k_qproj(const unsigned short* __restrict__ outs_bf,
             const float* __restrict__ attn_w, const float* __restrict__ attn_b,
             unsigned short* __restrict__ q_bf)
{
    __shared__ __align__(16) unsigned short lA[128 * 128];
    __shared__ __align__(16) unsigned short lB[128 * 128];
    const int tid   = threadIdx.x;
    const int mbase = blockIdx.x * 128;

    for (int c = tid; c < 2048; c += 256) {
        int row = c >> 4, k8 = c & 15;
        uint4 v = *(const uint4*)(outs_bf + ((size_t)(mbase + row)) * 128 + k8 * 8);
        *(uint4*)&lA[row * 128 + ((k8 ^ (row & 15)) << 3)] = v;
    }
    for (int c = tid; c < 2048; c += 256) {
        int row = c >> 4, k8 = c & 15;
        const float4* p = (const float4*)(attn_w + row * 128 + k8 * 8);
        float4 f0 = p[0], f1 = p[1];
        uint4 vv;
        vv.x = (unsigned int)f2bf(f0.x) | ((unsigned int)f2bf(f0.y) << 16);
        vv.y = (unsigned int)f2bf(f0.z) | ((unsigned int)f2bf(f0.w) << 16);
        vv.z = (unsigned int)f2bf(f1.x) | ((unsigned int)f2bf(f1.y) << 16);
        vv.w = (unsigned int)f2bf(f1.z) | ((unsigned int)f2bf(f1.w) << 16);
        *(uint4*)&lB[row * 128 + ((k8 ^ (row & 15)) << 3)] = vv;
    }
    __syncthreads();

    const int w = tid >> 6, lane = tid & 63, quad = lane >> 4, l16 = lane & 15;
    f32x4 acc[2][8];
#pragma unroll
    for (int r = 0; r < 2; ++r)
#pragma unroll
        for (int n = 0; n < 8; ++n) acc[r][n] = (f32x4){0.f, 0.f, 0.f, 0.f};

#pragma unroll
    for (int ks = 0; ks < 4; ++ks) {
        int k8 = ks * 4 + quad;
        short8 af[2];
#pragma unroll
        for (int r = 0; r < 2; ++r) {
            int row = w * 32 + r * 16 + l16;
            af[r] = *(const short8*)&lA[row * 128 + ((k8 ^ (row & 15)) << 3)];
        }
        short8 bfr[8];
#pragma unroll
        for (int n = 0; n < 8; ++n) {
            int col = n * 16 + l16;
            bfr[n] = *(const short8*)&lB[col * 128 + ((k8 ^ (col & 15)) << 3)];
        }
#pragma unroll
        for (int r = 0; r < 2; ++r)
#pragma unroll
            for (int n = 0; n < 8; ++n)
                acc[r][n] = __builtin_amdgcn_mfma_f32_16x16x32_bf16(
                    af[r], bfr[n], acc[r][n], 0, 0, 0);
    }
#pragma unroll
    for (int n = 0; n < 8; ++n) {
        int col = n * 16 + l16;
        float bias = attn_b[col];
#pragma unroll
        for (int r = 0; r < 2; ++r)
#pragma unroll
            for (int reg = 0; reg < 4; ++reg) {
                int row = w * 32 + r * 16 + quad * 4 + reg;
                q_bf[((size_t)(mbase + row)) * 128 + col] =
                    f2bf(acc[r][n][reg] + bias);
            }
    }
}

// K4: scores[b][q][k] = (Q[b][q] . outs[b][k]) / sqrt(H), causal tiles only
__global__ __launch_bounds__(256, 2)
void k_scores(const unsigned short* __restrict__ q_bf,
              const unsigned short* __restrict__ outs_bf,
              unsigned short* __restrict__ sc, int b0)
{
    const int kt = blockIdx.x, qt = blockIdx.y, bl = blockIdx.z;
    if (kt > qt) return;
    const int b = b0 + bl;

    __shared__ __align__(16) unsigned short lA[128 * 128];
    __shared__ __align__(16) unsigned short lB[128 * 128];
    const int tid = threadIdx.x;

    for (int c = tid; c < 2048; c += 256) {
        int row = c >> 4, k8 = c & 15;
        uint4 va = *(const uint4*)(q_bf +
            ((size_t)(b * 1024 + qt * 128 + row)) * 128 + k8 * 8);
        *(uint4*)&lA[row * 128 + ((k8 ^ (row & 15)) << 3)] = va;
        uint4 vb = *(const uint4*)(outs_bf +
            ((size_t)(b * 1024 + kt * 128 + row)) * 128 + k8 * 8);
        *(uint4*)&lB[row * 128 + ((k8 ^ (row & 15)) << 3)] = vb;
    }
    __syncthreads();

    const int w = tid >> 6, lane = tid & 63, quad = lane >> 4, l16 = lane & 15;
    f32x4 acc[2][8];
#pragma unroll
    for (int r = 0; r < 2; ++r)
#pragma unroll
        for (int n = 0; n < 8; ++n) acc[r][n] = (f32x4){0.f, 0.f, 0.f, 0.f};

#pragma unroll
    for (int ks = 0; ks < 4; ++ks) {
        int k8 = ks * 4 + quad;
        short8 af[2];
#pragma unroll
        for (int r = 0; r < 2; ++r) {
            int row = w * 32 + r * 16 + l16;
            af[r] = *(const short8*)&lA[row * 128 + ((k8 ^ (row & 15)) << 3)];
        }
        short8 bfr[8];
#pragma unroll
        for (int n = 0; n < 8; ++n) {
            int col = n * 16 + l16;
            bfr[n] = *(const short8*)&lB[col * 128 + ((k8 ^ (col & 15)) << 3)];
        }
#pragma unroll
        for (int r = 0; r < 2; ++r)
#pragma unroll
            for (int n = 0; n < 8; ++n)
                acc[r][n] = __builtin_amdgcn_mfma_f32_16x16x32_bf16(
                    af[r], bfr[n], acc[r][n], 0, 0, 0);
    }
    const float scale = 0.08838834764831845f;  // 1/sqrt(128)
#pragma unroll
    for (int n = 0; n < 8; ++n) {
        int col = n * 16 + l16;
#pragma unroll
        for (int r = 0; r < 2; ++r)
#pragma unroll
            for (int reg = 0; reg < 4; ++reg) {
                int row = w * 32 + r * 16 + quad * 4 + reg;
                sc[((size_t)(bl * 1024 + qt * 128 + row)) * 1024 + kt * 128 + col] =
                    f2bf(acc[r][n][reg] * scale);
            }
    }
}

// K5: causal softmax in place (bf16)
__global__ __launch_bounds__(256)
void k_softmax(unsigned short* __restrict__ sc)
{
    const int tid = threadIdx.x, w = tid >> 6, lane = tid & 63;
    const int r = blockIdx.x * 4 + w;           // row within chunk
    const int q = r & 1023;
    unsigned int* row = (unsigned int*)sc + (size_t)r * 512;
    const int nIter = (q >> 7) + 1;             // 128-element groups written

    float m = -1e30f, l = 0.f;
    for (int ii = 0; ii < nIter; ++ii) {
        int k2 = lane + (ii << 6);
        unsigned int u = row[k2];
        float a  = bf2f((unsigned short)(u & 0xffffu));
        float bq = bf2f((unsigned short)(u >> 16));
        float mt = fmaxf((2 * k2 <= q) ? a : -1e30f,
                         (2 * k2 + 1 <= q) ? bq : -1e30f);
        float mn = fmaxf(m, mt);
        float ea = (2 * k2     <= q) ? __expf(a  - mn) : 0.f;
        float eb = (2 * k2 + 1 <= q) ? __expf(bq - mn) : 0.f;
        l = l * __expf(m - mn) + ea + eb;
        m = mn;
    }
#pragma unroll
    for (int off = 1; off < 64; off <<= 1) {
        float m2 = __shfl_xor(m, off, 64);
        float l2 = __shfl_xor(l, off, 64);
        float mn = fmaxf(m, m2);
        l = l * __expf(m - mn) + l2 * __expf(m2 - mn);
        m = mn;
    }
    float inv = 1.0f / l;
    for (int ii = 0; ii < nIter; ++ii) {
        int k2 = lane + (ii << 6);
        unsigned int u = row[k2];
        float a  = bf2f((unsigned short)(u & 0xffffu));
        float bq = bf2f((unsigned short)(u >> 16));
        float pa = (2 * k2     <= q) ? __expf(a  - m) * inv : 0.f;
        float pb = (2 * k2 + 1 <= q) ? __expf(bq - m) * inv : 0.f;
        row[k2] = (unsigned int)f2bf(pa) | ((unsigned int)f2bf(pb) << 16);
    }
}

// K6: ctx[b][q][d] = P[b][q][s] @ V[s][d]  (V = outs, B-frag from outsT)
__global__ __launch_bounds__(256, 2)
void k_pv(const unsigned short* __restrict__ pr,
          const unsigned short* __restrict__ outsT,
          float* __restrict__ ctx, int b0)
{
    const int qt = blockIdx.x, bl = blockIdx.y;
    const int b = b0 + bl;
    __shared__ __align__(16) unsigned short lA[128 * 64];
    __shared__ __align__(16) unsigned short lB[128 * 64];
    const int tid = threadIdx.x;
    const int w = tid >> 6, lane = tid & 63, quad = lane >> 4, l16 = lane & 15;

    f32x4 acc[2][8];
#pragma unroll
    for (int r = 0; r < 2; ++r)
#pragma unroll
        for (int n = 0; n < 8; ++n) acc[r][n] = (f32x4){0.f, 0.f, 0.f, 0.f};

    const int stmax = 2 * qt + 1;
    for (int st = 0; st <= stmax; ++st) {
        __syncthreads();
        for (int c = tid; c < 1024; c += 256) {
            int row = c >> 3, k8 = c & 7;
            uint4 va = *(const uint4*)(pr +
                ((size_t)(bl * 1024 + qt * 128 + row)) * 1024 + st * 64 + k8 * 8);
            *(uint4*)&lA[row * 64 + ((k8 ^ (row & 7)) << 3)] = va;
            uint4 vb = *(const uint4*)(outsT +
                ((size_t)(b * 128 + row)) * 1024 + st * 64 + k8 * 8);
            *(uint4*)&lB[row * 64 + ((k8 ^ (row & 7)) << 3)] = vb;
        }
        __syncthreads();
#pragma unroll
        for (int ks = 0; ks < 2; ++ks) {
            int k8 = ks * 4 + quad;
            short8 af[2];
#pragma unroll
            for (int r = 0; r < 2; ++r) {
                int row = w * 32 + r * 16 + l16;
                af[r] = *(const short8*)&lA[row * 64 + ((k8 ^ (row & 7)) << 3)];
            }
            short8 bfr[8];
#pragma unroll
            for (int n = 0; n < 8; ++n) {
                int col = n * 16 + l16;
                bfr[n] = *(const short8*)&lB[col * 64 + ((k8 ^ (col & 7)) << 3)];
            }
#pragma unroll
            for (int r = 0; r < 2; ++r)
#pragma unroll
                for (int n = 0; n < 8; ++n)
                    acc[r][n] = __builtin_amdgcn_mfma_f32_16x16x32_bf16(
                        af[r], bfr[n], acc[r][n], 0, 0, 0);
        }
    }
#pragma unroll
    for (int n = 0; n < 8; ++n) {
        int col = n * 16 + l16;
#pragma unroll
        for (int r = 0; r < 2; ++r)
#pragma unroll
            for (int reg = 0; reg < 4; ++reg) {
                int row = w * 32 + r * 16 + quad * 4 + reg;
                ctx[((size_t)(b * 1024) + qt * 128 + row) * 128 + col] =
                    acc[r][n][reg];
            }
    }
}

// K7: logits = [outs | ctx] @ fc_w.T + fc_b   (V=55, K=256)
__global__ __launch_bounds__(256, 2)
void k_fc(const unsigned short* __restrict__ outs_bf,
          const float* __restrict__ ctx,
          const float* __restrict__ fc_w, const float* __restrict__ fc_b,
          float* __restrict__ out)
{
    __shared__ float lw[55 * 257];
    __shared__ float comb[256];
    __shared__ float part[256];
    const int tid = threadIdx.x;
    const int c = tid >> 6, v = tid & 63;

    for (int idx = tid; idx < 55 * 256; idx += 256) {
        int rr = idx >> 8, cc = idx & 255;
        lw[rr * 257 + cc] = fc_w[idx];
    }
    __syncthreads();

    const int t0 = blockIdx.x * 64;
    for (int t = 0; t < 64; ++t) {
        size_t bt = (size_t)(t0 + t);
        if (tid < 128) comb[tid] = bf2f(outs_bf[bt * 128 + tid]);
        else           comb[tid] = ctx[bt * 128 + (tid - 128)];
        __syncthreads();
        float p0 = 0.f, p1 = 0.f, p2 = 0.f, p3 = 0.f;
        if (v < 55) {
            const float* wr = lw + v * 257 + c * 64;
            const float* cb = comb + c * 64;
#pragma unroll
            for (int j = 0; j < 16; ++j) {
                p0 += wr[4*j]   * cb[4*j];
                p1 += wr[4*j+1] * cb[4*j+1];
                p2 += wr[4*j+2] * cb[4*j+2];
                p3 += wr[4*j+3] * cb[4*j+3];
            }
        }
        part[tid] = (p0 + p1) + (p2 + p3);
        __syncthreads();
        if (tid < 55) {
            out[bt * 55 + tid] = fc_b[tid] + part[tid] + part[64 + tid] +
                                 part[128 + tid] + part[192 + tid];
        }
        __syncthreads();
    }
}

// ---------------------------------------------------------------------------
extern "C" void kernel_launch(void* const* d_in, const int* in_sizes, int n_in,
                              void* d_out, int out_size, void* d_ws, size_t ws_size,
                              hipStream_t stream)
{
    const int*   x      = (const int*)d_in[0];
    const float* emb    = (const float*)d_in[1];
    const float* w_ih0  = (const float*)d_in[2];
    const float* b_ih0  = (const float*)d_in[3];
    const float* w_hh0  = (const float*)d_in[4];
    const float* b_hh0  = (const float*)d_in[5];
    const float* w_ih1  = (const float*)d_in[6];
    const float* b_ih1  = (const float*)d_in[7];
    const float* w_hh1  = (const float*)d_in[8];
    const float* b_hh1  = (const float*)d_in[9];
    const float* attn_w = (const float*)d_in[10];
    const float* attn_b = (const float*)d_in[11];
    const float* fc_w   = (const float*)d_in[12];
    const float* fc_b   = (const float*)d_in[13];
    float* out = (float*)d_out;

    char* ws = (char*)d_ws;
    unsigned short* outs_bf = (unsigned short*)(ws);                        // 16 MiB
    unsigned short* outsT   = (unsigned short*)(ws + ((size_t)16 << 20));   // 16 MiB
    unsigned short* q_bf    = (unsigned short*)(ws + ((size_t)32 << 20));   // 16 MiB
    float*          ctx     = (float*)         (ws + ((size_t)48 << 20));   // 32 MiB
    float*          WEp     = (float*)         (ws + ((size_t)80 << 20));   // 28 KiB
    float*          WEg     = (float*)         (ws + ((size_t)81 << 20));   // 32 MiB
    unsigned short* sc      = (unsigned short*)(ws + ((size_t)113 << 20));  // CB*2 MiB

    size_t fixed = (size_t)113 << 20;
    size_t avail = (ws_size > fixed) ? (ws_size - fixed) : 0;
    int CB = (int)(avail / ((size_t)2 << 20));
    if (CB < 1)  CB = 1;
    if (CB > 64) CB = 64;

    k_we<<<dim3(55), dim3(128), 0, stream>>>(emb, w_ih0, b_ih0, b_hh0, WEp);
    k_weg<<<dim3(32, 64), dim3(256), 0, stream>>>(x, WEp, WEg);
    k_scan3<<<dim3(4), dim3(512), 0, stream>>>(
        WEg, w_hh0, w_ih1, b_ih1, w_hh1, b_hh1, outs_bf);
    k_transpose<<<dim3(8, 64), dim3(256), 0, stream>>>(outs_bf, outsT);
    k_qproj<<<dim3(512), dim3(256), 0, stream>>>(outs_bf, attn_w, attn_b, q_bf);

    for (int b0 = 0; b0 < 64; b0 += CB) {
        int nb = 64 - b0; if (nb > CB) nb = CB;
        k_scores <<<dim3(8, 8, nb), dim3(256), 0, stream>>>(q_bf, outs_bf, sc, b0);
        k_softmax<<<dim3(nb * 256), dim3(256), 0, stream>>>(sc);
        k_pv     <<<dim3(8, nb),   dim3(256), 0, stream>>>(sc, outsT, ctx, b0);
    }
    k_fc<<<dim3(1024), dim3(256), 0, stream>>>(outs_bf, ctx, fc_w, fc_b, out);
}

// Round 4
// 1009.791 us; speedup vs baseline: 1.4590x; 1.4590x over previous
//
#include <hip/hip_runtime.h>
#include <hip/hip_bf16.h>
#include <cstdint>
#include <cstddef>

// ---------------------------------------------------------------------------
// RNNAttentionModel: embed -> 2-layer tanh RNN scan (MFMA-batched) ->
// causal self-attention (bf16 MFMA GEMMs) -> concat -> FC(55)
// B=64 T=1024 E=64 H=128 V=55
// ---------------------------------------------------------------------------

typedef __attribute__((ext_vector_type(8))) short short8;   // 8 x bf16 frag
typedef __attribute__((ext_vector_type(4))) float f32x4;

__device__ __forceinline__ float bf2f(unsigned short u) {
    union { unsigned int i; float f; } c; c.i = ((unsigned int)u) << 16; return c.f;
}
__device__ __forceinline__ unsigned short f2bf(float f) {
    union { float f; unsigned int i; } c; c.f = f;
    unsigned int u = c.i;
    u += 0x7fffu + ((u >> 16) & 1u);   // RNE
    return (unsigned short)(u >> 16);
}
// v_cvt_pk_bf16_f32: pack two fp32 -> bf16x2 in one instruction
__device__ __forceinline__ unsigned int pk_bf16(float lo, float hi) {
    union { __hip_bfloat162 h2; unsigned int u; } c;
    c.h2 = __float22bfloat162_rn(make_float2(lo, hi));
    return c.u;
}
// tanh without the full-precision divide: v_rcp_f32 is ~1ulp, plenty for bf16
__device__ __forceinline__ float fast_tanh(float x) {
    float e = __expf(2.0f * x);
    return 1.0f - 2.0f * __builtin_amdgcn_rcpf(e + 1.0f);
}
// Raw workgroup barrier: waits LDS ops only; global loads/stores stay in
// flight (avoids the vmcnt(0) drain __syncthreads() would emit every step).
__device__ __forceinline__ void bar_lds() {
    asm volatile("s_waitcnt lgkmcnt(0)\n\ts_barrier" ::: "memory");
}

// ---------------------------------------------------------------------------
// K0a: WE[v][i] = w_ih0[i,:] . emb[v,:] + b_ih0[i] + b_hh0[i]   (55 x 128)
// ---------------------------------------------------------------------------
__global__ __launch_bounds__(128)
void k_we(const float* __restrict__ emb, const float* __restrict__ w_ih0,
          const float* __restrict__ b_ih0, const float* __restrict__ b_hh0,
          float* __restrict__ WE)
{
    __shared__ float ev[64];
    const int i = threadIdx.x;
    const int v = blockIdx.x;
    if (i < 64) ev[i] = emb[v * 64 + i];
    __syncthreads();
    float s = b_ih0[i] + b_hh0[i];
    const float* wr = w_ih0 + i * 64;
#pragma unroll
    for (int k = 0; k < 64; ++k) s += wr[k] * ev[k];
    WE[v * 128 + i] = s;
}

// ---------------------------------------------------------------------------
// K0b: WEg[b][t][:] = WE[x[b][t]][:]   (pre-gathered layer-0 pre-activation)
// ---------------------------------------------------------------------------
__global__ __launch_bounds__(256)
void k_weg(const int* __restrict__ x, const float* __restrict__ WE,
           float* __restrict__ WEg)
{
    __shared__ int xv[32];
    const int tid = threadIdx.x;
    const int b   = blockIdx.y;
    const int t0  = blockIdx.x * 32;
    if (tid < 32) xv[tid] = x[b * 1024 + t0 + tid];
    __syncthreads();
#pragma unroll
    for (int it = 0; it < 4; ++it) {
        int tt = it * 8 + (tid >> 5);
        int c4 = tid & 31;
        float4 v = ((const float4*)(WE + xv[tt] * 128))[c4];
        ((float4*)(WEg + ((size_t)b * 1024 + t0 + tt) * 128))[c4] = v;
    }
}

// ---------------------------------------------------------------------------
// K1: MFMA-batched RNN scan. 4 blocks x 16 batches, 512 threads (8 waves).
// Wave w owns M-tile rows 16w..16w+15 of Whh0 / Wih1 / Whh1 as stationary
// bf16 A-frags (48 VGPRs). h-state (bf16) lives in LDS as B-frag layout
// [batch][k] (stride 136 shorts), double-buffered -> ONE barrier per step.
// h1 is stored straight to global (uint2; never waited inside the loop).
// WEg[t+1] rides in the MFMA C-init; prefetch depth 2 covers HBM latency.
// ---------------------------------------------------------------------------
__global__ __launch_bounds__(512, 1)
void k_scan3(const float* __restrict__ WEg,
             const float* __restrict__ w_hh0,
             const float* __restrict__ w_ih1, const float* __restrict__ b_ih1,
             const float* __restrict__ w_hh1, const float* __restrict__ b_hh1,
             unsigned short* __restrict__ outs_bf)
{
    const int tid   = threadIdx.x;
    const int w     = tid >> 6;          // wave 0..7 -> rows 16w..16w+15
    const int lane  = tid & 63;
    const int quad  = lane >> 4;
    const int n     = lane & 15;         // batch col
    const int bbase = blockIdx.x * 16;
    const int rowo  = w * 16 + quad * 4;

    __shared__ __align__(16) unsigned short h0buf[2][16][136];
    __shared__ __align__(16) unsigned short h1buf[2][16][136];

    // ---- stationary A fragments (bf16): lane holds A[m=n][k=32ks+8q+j] ----
    short8 a0[4], a1[4], a2[4];
    {
        const size_t mrow = (size_t)(w * 16 + n) * 128;
#pragma unroll
        for (int ks = 0; ks < 4; ++ks) {
            const int ko = ks * 32 + quad * 8;
            const float4* p0 = (const float4*)(w_hh0 + mrow + ko);
            const float4* p1 = (const float4*)(w_ih1 + mrow + ko);
            const float4* p2 = (const float4*)(w_hh1 + mrow + ko);
            float4 f0 = p0[0], f1 = p0[1];
            short8 r;
            r[0]=(short)f2bf(f0.x); r[1]=(short)f2bf(f0.y);
            r[2]=(short)f2bf(f0.z); r[3]=(short)f2bf(f0.w);
            r[4]=(short)f2bf(f1.x); r[5]=(short)f2bf(f1.y);
            r[6]=(short)f2bf(f1.z); r[7]=(short)f2bf(f1.w);
            a0[ks] = r;
            f0 = p1[0]; f1 = p1[1];
            r[0]=(short)f2bf(f0.x); r[1]=(short)f2bf(f0.y);
            r[2]=(short)f2bf(f0.z); r[3]=(short)f2bf(f0.w);
            r[4]=(short)f2bf(f1.x); r[5]=(short)f2bf(f1.y);
            r[6]=(short)f2bf(f1.z); r[7]=(short)f2bf(f1.w);
            a1[ks] = r;
            f0 = p2[0]; f1 = p2[1];
            r[0]=(short)f2bf(f0.x); r[1]=(short)f2bf(f0.y);
            r[2]=(short)f2bf(f0.z); r[3]=(short)f2bf(f0.w);
            r[4]=(short)f2bf(f1.x); r[5]=(short)f2bf(f1.y);
            r[6]=(short)f2bf(f1.z); r[7]=(short)f2bf(f1.w);
            a2[ks] = r;
        }
    }
    // layer-1 bias as an MFMA C-initializer (C[row=quad*4+r][col=n])
    f32x4 b1i;
#pragma unroll
    for (int r = 0; r < 4; ++r) b1i[r] = b_ih1[rowo + r] + b_hh1[rowo + r];

    // ---- prologue ----
    const size_t wegBase = ((size_t)(bbase + n)) * 1024 * 128 + rowo;
    {
        unsigned int* z = (unsigned int*)&h1buf[0][0][0];
        for (int i2 = tid; i2 < 16 * 136 / 2; i2 += 512) z[i2] = 0u;
        float4 w0 = *(const float4*)(WEg + wegBase);          // t = 0
        unsigned int lo = pk_bf16(fast_tanh(w0.x), fast_tanh(w0.y));
        unsigned int hi = pk_bf16(fast_tanh(w0.z), fast_tanh(w0.w));
        *(uint2*)&h0buf[0][n][rowo] = make_uint2(lo, hi);
    }
    float4 wegA = *(const float4*)(WEg + wegBase + 128);      // t = 1
    float4 wegB = *(const float4*)(WEg + wegBase + 256);      // t = 2
    unsigned short* outp = outs_bf + ((size_t)(bbase + n)) * 131072 + rowo;
    __syncthreads();

    for (int t = 0; t < 1024; ++t) {
        const int p = t & 1;
        // ---- B-fragments: h0(t), h1(t-1) ----
        const unsigned short* h0p = &h0buf[p][n][quad * 8];
        const unsigned short* h1p = &h1buf[p][n][quad * 8];
        short8 bh0[4], bh1[4];
#pragma unroll
        for (int ks = 0; ks < 4; ++ks) {
            bh0[ks] = *(const short8*)(h0p + ks * 32);
            bh1[ks] = *(const short8*)(h1p + ks * 32);
        }
        f32x4 c0  = (f32x4){wegA.x, wegA.y, wegA.z, wegA.w};
        f32x4 c1a = b1i;
        f32x4 c1b = (f32x4){0.f, 0.f, 0.f, 0.f};
#pragma unroll
        for (int ks = 0; ks < 4; ++ks) {
            c0  = __builtin_amdgcn_mfma_f32_16x16x32_bf16(a0[ks], bh0[ks], c0, 0,0,0);
            c1a = __builtin_amdgcn_mfma_f32_16x16x32_bf16(a1[ks], bh0[ks], c1a,0,0,0);
            c1b = __builtin_amdgcn_mfma_f32_16x16x32_bf16(a2[ks], bh1[ks], c1b,0,0,0);
        }
        // rotate WEg pipeline (depth 2)
        wegA = wegB;
        int tpre = (t + 3 < 1024) ? (t + 3) : 1023;
        wegB = *(const float4*)(WEg + wegBase + (size_t)tpre * 128);

        // ---- activations ----
        float h00 = fast_tanh(c0[0]);
        float h01 = fast_tanh(c0[1]);
        float h02 = fast_tanh(c0[2]);
        float h03 = fast_tanh(c0[3]);
        float h10 = fast_tanh(c1a[0] + c1b[0]);
        float h11 = fast_tanh(c1a[1] + c1b[1]);
        float h12 = fast_tanh(c1a[2] + c1b[2]);
        float h13 = fast_tanh(c1a[3] + c1b[3]);

        unsigned int l0 = pk_bf16(h00, h01), l1 = pk_bf16(h02, h03);
        unsigned int m0 = pk_bf16(h10, h11), m1 = pk_bf16(h12, h13);
        *(uint2*)&h0buf[p ^ 1][n][rowo] = make_uint2(l0, l1);
        *(uint2*)&h1buf[p ^ 1][n][rowo] = make_uint2(m0, m1);
        *(uint2*)(outp + (size_t)t * 128) = make_uint2(m0, m1);  // h1 -> global
        bar_lds();
    }
}

// ---------------------------------------------------------------------------
// K2: outs [b][t][h] -> outsT [b][h][t]  (LDS tile transpose)
// ---------------------------------------------------------------------------
__global__ __launch_bounds__(256)
void k_transpose(const unsigned short* __restrict__ outs_bf,
                 unsigned short* __restrict__ outsT)
{
    __shared__ unsigned short lt[128][130];
    const int tid = threadIdx.x;
    const int t0  = blockIdx.x * 128;
    const int b   = blockIdx.y;
    const unsigned int* src =
        (const unsigned int*)(outs_bf + ((size_t)b * 1024 + t0) * 128);
    for (int idx = tid; idx < 8192; idx += 256) {
        int tr = idx >> 6, h2 = idx & 63;
        unsigned int v = src[tr * 64 + h2];
        lt[tr][h2 * 2]     = (unsigned short)(v & 0xffffu);
        lt[tr][h2 * 2 + 1] = (unsigned short)(v >> 16);
    }
    __syncthreads();
    unsigned int* dst = (unsigned int*)(outsT + (size_t)b * 128 * 1024);
    for (int idx = tid; idx < 8192; idx += 256) {
        int h = idx >> 6, t2 = idx & 63;
        unsigned int v = (unsigned int)lt[t2 * 2][h] |
                         ((unsigned int)lt[t2 * 2 + 1][h] << 16);
        dst[h * 512 + (t0 >> 1) + t2] = v;
    }
}

// ---------------------------------------------------------------------------
// MFMA GEMM core conventions (16x16x32 bf16):
//   A frag: lane holds A[m=16*tile+(lane&15)][k = 8*(lane>>4) .. +7]
//   B frag: lane holds B[k][n] gathered as Brow[n=16*tile+(lane&15)][same k]
//   C/D   : col = lane&15, row = 4*(lane>>4) + reg
// LDS layout [row][k], 16B chunks XOR-swizzled: phys_k8 = k8 ^ (row & mask)
// ---------------------------------------------------------------------------

// K3: Q = outs @ attn_w.T + attn_b   (M = B*T, N = K = 128, one LDS pass)
__global__ __launch_bounds__(256, 2)
void k_qproj(const unsigned short* __restrict__ outs_bf,
             const float* __restrict__ attn_w, const float* __restrict__ attn_b,
             unsigned short* __restrict__ q_bf)
{
    __shared__ __align__(16) unsigned short lA[128 * 128];
    __shared__ __align__(16) unsigned short lB[128 * 128];
    const int tid   = threadIdx.x;
    const int mbase = blockIdx.x * 128;

    for (int c = tid; c < 2048; c += 256) {
        int row = c >> 4, k8 = c & 15;
        uint4 v = *(const uint4*)(outs_bf + ((size_t)(mbase + row)) * 128 + k8 * 8);
        *(uint4*)&lA[row * 128 + ((k8 ^ (row & 15)) << 3)] = v;
    }
    for (int c = tid; c < 2048; c += 256) {
        int row = c >> 4, k8 = c & 15;
        const float4* p = (const float4*)(attn_w + row * 128 + k8 * 8);
        float4 f0 = p[0], f1 = p[1];
        uint4 vv;
        vv.x = (unsigned int)f2bf(f0.x) | ((unsigned int)f2bf(f0.y) << 16);
        vv.y = (unsigned int)f2bf(f0.z) | ((unsigned int)f2bf(f0.w) << 16);
        vv.z = (unsigned int)f2bf(f1.x) | ((unsigned int)f2bf(f1.y) << 16);
        vv.w = (unsigned int)f2bf(f1.z) | ((unsigned int)f2bf(f1.w) << 16);
        *(uint4*)&lB[row * 128 + ((k8 ^ (row & 15)) << 3)] = vv;
    }
    __syncthreads();

    const int w = tid >> 6, lane = tid & 63, quad = lane >> 4, l16 = lane & 15;
    f32x4 acc[2][8];
#pragma unroll
    for (int r = 0; r < 2; ++r)
#pragma unroll
        for (int n = 0; n < 8; ++n) acc[r][n] = (f32x4){0.f, 0.f, 0.f, 0.f};

#pragma unroll
    for (int ks = 0; ks < 4; ++ks) {
        int k8 = ks * 4 + quad;
        short8 af[2];
#pragma unroll
        for (int r = 0; r < 2; ++r) {
            int row = w * 32 + r * 16 + l16;
            af[r] = *(const short8*)&lA[row * 128 + ((k8 ^ (row & 15)) << 3)];
        }
        short8 bfr[8];
#pragma unroll
        for (int n = 0; n < 8; ++n) {
            int col = n * 16 + l16;
            bfr[n] = *(const short8*)&lB[col * 128 + ((k8 ^ (col & 15)) << 3)];
        }
#pragma unroll
        for (int r = 0; r < 2; ++r)
#pragma unroll
            for (int n = 0; n < 8; ++n)
                acc[r][n] = __builtin_amdgcn_mfma_f32_16x16x32_bf16(
                    af[r], bfr[n], acc[r][n], 0, 0, 0);
    }
#pragma unroll
    for (int n = 0; n < 8; ++n) {
        int col = n * 16 + l16;
        float bias = attn_b[col];
#pragma unroll
        for (int r = 0; r < 2; ++r)
#pragma unroll
            for (int reg = 0; reg < 4; ++reg) {
                int row = w * 32 + r * 16 + quad * 4 + reg;
                q_bf[((size_t)(mbase + row)) * 128 + col] =
                    f2bf(acc[r][n][reg] + bias);
            }
    }
}

// K4: scores[b][q][k] = (Q[b][q] . outs[b][k]) / sqrt(H), causal tiles only
__global__ __launch_bounds__(256, 2)
void k_scores(const unsigned short* __restrict__ q_bf,
              const unsigned short* __restrict__ outs_bf,
              unsigned short* __restrict__ sc, int b0)
{
    const int kt = blockIdx.x, qt = blockIdx.y, bl = blockIdx.z;
    if (kt > qt) return;
    const int b = b0 + bl;

    __shared__ __align__(16) unsigned short lA[128 * 128];
    __shared__ __align__(16) unsigned short lB[128 * 128];
    const int tid = threadIdx.x;

    for (int c = tid; c < 2048; c += 256) {
        int row = c >> 4, k8 = c & 15;
        uint4 va = *(const uint4*)(q_bf +
            ((size_t)(b * 1024 + qt * 128 + row)) * 128 + k8 * 8);
        *(uint4*)&lA[row * 128 + ((k8 ^ (row & 15)) << 3)] = va;
        uint4 vb = *(const uint4*)(outs_bf +
            ((size_t)(b * 1024 + kt * 128 + row)) * 128 + k8 * 8);
        *(uint4*)&lB[row * 128 + ((k8 ^ (row & 15)) << 3)] = vb;
    }
    __syncthreads();

    const int w = tid >> 6, lane = tid & 63, quad = lane >> 4, l16 = lane & 15;
    f32x4 acc[2][8];
#pragma unroll
    for (int r = 0; r < 2; ++r)
#pragma unroll
        for (int n = 0; n < 8; ++n) acc[r][n] = (f32x4){0.f, 0.f, 0.f, 0.f};

#pragma unroll
    for (int ks = 0; ks < 4; ++ks) {
        int k8 = ks * 4 + quad;
        short8 af[2];
#pragma unroll
        for (int r = 0; r < 2; ++r) {
            int row = w * 32 + r * 16 + l16;
            af[r] = *(const short8*)&lA[row * 128 + ((k8 ^ (row & 15)) << 3)];
        }
        short8 bfr[8];
#pragma unroll
        for (int n = 0; n < 8; ++n) {
            int col = n * 16 + l16;
            bfr[n] = *(const short8*)&lB[col * 128 + ((k8 ^ (col & 15)) << 3)];
        }
#pragma unroll
        for (int r = 0; r < 2; ++r)
#pragma unroll
            for (int n = 0; n < 8; ++n)
                acc[r][n] = __builtin_amdgcn_mfma_f32_16x16x32_bf16(
                    af[r], bfr[n], acc[r][n], 0, 0, 0);
    }
    const float scale = 0.08838834764831845f;  // 1/sqrt(128)
#pragma unroll
    for (int n = 0; n < 8; ++n) {
        int col = n * 16 + l16;
#pragma unroll
        for (int r = 0; r < 2; ++r)
#pragma unroll
            for (int reg = 0; reg < 4; ++reg) {
                int row = w * 32 + r * 16 + quad * 4 + reg;
                sc[((size_t)(bl * 1024 + qt * 128 + row)) * 1024 + kt * 128 + col] =
                    f2bf(acc[r][n][reg] * scale);
            }
    }
}

// K5: causal softmax in place (bf16)
__global__ __launch_bounds__(256)
void k_softmax(unsigned short* __restrict__ sc)
{
    const int tid = threadIdx.x, w = tid >> 6, lane = tid & 63;
    const int r = blockIdx.x * 4 + w;           // row within chunk
    const int q = r & 1023;
    unsigned int* row = (unsigned int*)sc + (size_t)r * 512;
    const int nIter = (q >> 7) + 1;             // 128-element groups written

    float m = -1e30f, l = 0.f;
    for (int ii = 0; ii < nIter; ++ii) {
        int k2 = lane + (ii << 6);
        unsigned int u = row[k2];
        float a  = bf2f((unsigned short)(u & 0xffffu));
        float bq = bf2f((unsigned short)(u >> 16));
        float mt = fmaxf((2 * k2 <= q) ? a : -1e30f,
                         (2 * k2 + 1 <= q) ? bq : -1e30f);
        float mn = fmaxf(m, mt);
        float ea = (2 * k2     <= q) ? __expf(a  - mn) : 0.f;
        float eb = (2 * k2 + 1 <= q) ? __expf(bq - mn) : 0.f;
        l = l * __expf(m - mn) + ea + eb;
        m = mn;
    }
#pragma unroll
    for (int off = 1; off < 64; off <<= 1) {
        float m2 = __shfl_xor(m, off, 64);
        float l2 = __shfl_xor(l, off, 64);
        float mn = fmaxf(m, m2);
        l = l * __expf(m - mn) + l2 * __expf(m2 - mn);
        m = mn;
    }
    float inv = 1.0f / l;
    for (int ii = 0; ii < nIter; ++ii) {
        int k2 = lane + (ii << 6);
        unsigned int u = row[k2];
        float a  = bf2f((unsigned short)(u & 0xffffu));
        float bq = bf2f((unsigned short)(u >> 16));
        float pa = (2 * k2     <= q) ? __expf(a  - m) * inv : 0.f;
        float pb = (2 * k2 + 1 <= q) ? __expf(bq - m) * inv : 0.f;
        row[k2] = (unsigned int)f2bf(pa) | ((unsigned int)f2bf(pb) << 16);
    }
}

// K6: ctx[b][q][d] = P[b][q][s] @ V[s][d]  (V = outs, B-frag from outsT)
__global__ __launch_bounds__(256, 2)
void k_pv(const unsigned short* __restrict__ pr,
          const unsigned short* __restrict__ outsT,
          float* __restrict__ ctx, int b0)
{
    const int qt = blockIdx.x, bl = blockIdx.y;
    const int b = b0 + bl;
    __shared__ __align__(16) unsigned short lA[128 * 64];
    __shared__ __align__(16) unsigned short lB[128 * 64];
    const int tid = threadIdx.x;
    const int w = tid >> 6, lane = tid & 63, quad = lane >> 4, l16 = lane & 15;

    f32x4 acc[2][8];
#pragma unroll
    for (int r = 0; r < 2; ++r)
#pragma unroll
        for (int n = 0; n < 8; ++n) acc[r][n] = (f32x4){0.f, 0.f, 0.f, 0.f};

    const int stmax = 2 * qt + 1;
    for (int st = 0; st <= stmax; ++st) {
        __syncthreads();
        for (int c = tid; c < 1024; c += 256) {
            int row = c >> 3, k8 = c & 7;
            uint4 va = *(const uint4*)(pr +
                ((size_t)(bl * 1024 + qt * 128 + row)) * 1024 + st * 64 + k8 * 8);
            *(uint4*)&lA[row * 64 + ((k8 ^ (row & 7)) << 3)] = va;
            uint4 vb = *(const uint4*)(outsT +
                ((size_t)(b * 128 + row)) * 1024 + st * 64 + k8 * 8);
            *(uint4*)&lB[row * 64 + ((k8 ^ (row & 7)) << 3)] = vb;
        }
        __syncthreads();
#pragma unroll
        for (int ks = 0; ks < 2; ++ks) {
            int k8 = ks * 4 + quad;
            short8 af[2];
#pragma unroll
            for (int r = 0; r < 2; ++r) {
                int row = w * 32 + r * 16 + l16;
                af[r] = *(const short8*)&lA[row * 64 + ((k8 ^ (row & 7)) << 3)];
            }
            short8 bfr[8];
#pragma unroll
            for (int n = 0; n < 8; ++n) {
                int col = n * 16 + l16;
                bfr[n] = *(const short8*)&lB[col * 64 + ((k8 ^ (col & 7)) << 3)];
            }
#pragma unroll
            for (int r = 0; r < 2; ++r)
#pragma unroll
                for (int n = 0; n < 8; ++n)
                    acc[r][n] = __builtin_amdgcn_mfma_f32_16x16x32_bf16(
                        af[r], bfr[n], acc[r][n], 0, 0, 0);
        }
    }
#pragma unroll
    for (int n = 0; n < 8; ++n) {
        int col = n * 16 + l16;
#pragma unroll
        for (int r = 0; r < 2; ++r)
#pragma unroll
            for (int reg = 0; reg < 4; ++reg) {
                int row = w * 32 + r * 16 + quad * 4 + reg;
                ctx[((size_t)(b * 1024) + qt * 128 + row) * 128 + col] =
                    acc[r][n][reg];
            }
    }
}

// K7: logits = [outs | ctx] @ fc_w.T + fc_b   (V=55, K=256)
__global__ __launch_bounds__(256, 2)
void k_fc(const unsigned short* __restrict__ outs_bf,
          const float* __restrict__ ctx,
          const float* __restrict__ fc_w, const float* __restrict__ fc_b,
          float* __restrict__ out)
{
    __shared__ float lw[55 * 257];
    __shared__ float comb[256];
    __shared__ float part[256];
    const int tid = threadIdx.x;
    const int c = tid >> 6, v = tid & 63;

    for (int idx = tid; idx < 55 * 256; idx += 256) {
        int rr = idx >> 8, cc = idx & 255;
        lw[rr * 257 + cc] = fc_w[idx];
    }
    __syncthreads();

    const int t0 = blockIdx.x * 64;
    for (int t = 0; t < 64; ++t) {
        size_t bt = (size_t)(t0 + t);
        if (tid < 128) comb[tid] = bf2f(outs_bf[bt * 128 + tid]);
        else           comb[tid] = ctx[bt * 128 + (tid - 128)];
        __syncthreads();
        float p0 = 0.f, p1 = 0.f, p2 = 0.f, p3 = 0.f;
        if (v < 55) {
            const float* wr = lw + v * 257 + c * 64;
            const float* cb = comb + c * 64;
#pragma unroll
            for (int j = 0; j < 16; ++j) {
                p0 += wr[4*j]   * cb[4*j];
                p1 += wr[4*j+1] * cb[4*j+1];
                p2 += wr[4*j+2] * cb[4*j+2];
                p3 += wr[4*j+3] * cb[4*j+3];
            }
        }
        part[tid] = (p0 + p1) + (p2 + p3);
        __syncthreads();
        if (tid < 55) {
            out[bt * 55 + tid] = fc_b[tid] + part[tid] + part[64 + tid] +
                                 part[128 + tid] + part[192 + tid];
        }
        __syncthreads();
    }
}

// ---------------------------------------------------------------------------
extern "C" void kernel_launch(void* const* d_in, const int* in_sizes, int n_in,
                              void* d_out, int out_size, void* d_ws, size_t ws_size,
                              hipStream_t stream)
{
    const int*   x      = (const int*)d_in[0];
    const float* emb    = (const float*)d_in[1];
    const float* w_ih0  = (const float*)d_in[2];
    const float* b_ih0  = (const float*)d_in[3];
    const float* w_hh0  = (const float*)d_in[4];
    const float* b_hh0  = (const float*)d_in[5];
    const float* w_ih1  = (const float*)d_in[6];
    const float* b_ih1  = (const float*)d_in[7];
    const float* w_hh1  = (const float*)d_in[8];
    const float* b_hh1  = (const float*)d_in[9];
    const float* attn_w = (const float*)d_in[10];
    const float* attn_b = (const float*)d_in[11];
    const float* fc_w   = (const float*)d_in[12];
    const float* fc_b   = (const float*)d_in[13];
    float* out = (float*)d_out;

    char* ws = (char*)d_ws;
    unsigned short* outs_bf = (unsigned short*)(ws);                        // 16 MiB
    unsigned short* outsT   = (unsigned short*)(ws + ((size_t)16 << 20));   // 16 MiB
    unsigned short* q_bf    = (unsigned short*)(ws + ((size_t)32 << 20));   // 16 MiB
    float*          ctx     = (float*)         (ws + ((size_t)48 << 20));   // 32 MiB
    float*          WEp     = (float*)         (ws + ((size_t)80 << 20));   // 28 KiB
    float*          WEg     = (float*)         (ws + ((size_t)81 << 20));   // 32 MiB
    unsigned short* sc      = (unsigned short*)(ws + ((size_t)113 << 20));  // CB*2 MiB

    size_t fixed = (size_t)113 << 20;
    size_t avail = (ws_size > fixed) ? (ws_size - fixed) : 0;
    int CB = (int)(avail / ((size_t)2 << 20));
    if (CB < 1)  CB = 1;
    if (CB > 64) CB = 64;

    k_we<<<dim3(55), dim3(128), 0, stream>>>(emb, w_ih0, b_ih0, b_hh0, WEp);
    k_weg<<<dim3(32, 64), dim3(256), 0, stream>>>(x, WEp, WEg);
    k_scan3<<<dim3(4), dim3(512), 0, stream>>>(
        WEg, w_hh0, w_ih1, b_ih1, w_hh1, b_hh1, outs_bf);
    k_transpose<<<dim3(8, 64), dim3(256), 0, stream>>>(outs_bf, outsT);
    k_qproj<<<dim3(512), dim3(256), 0, stream>>>(outs_bf, attn_w, attn_b, q_bf);

    for (int b0 = 0; b0 < 64; b0 += CB) {
        int nb = 64 - b0; if (nb > CB) nb = CB;
        k_scores <<<dim3(8, 8, nb), dim3(256), 0, stream>>>(q_bf, outs_bf, sc, b0);
        k_softmax<<<dim3(nb * 256), dim3(256), 0, stream>>>(sc);
        k_pv     <<<dim3(8, nb),   dim3(256), 0, stream>>>(sc, outsT, ctx, b0);
    }
    k_fc<<<dim3(1024), dim3(256), 0, stream>>>(outs_bf, ctx, fc_w, fc_b, out);
}

// Round 5
// 968.853 us; speedup vs baseline: 1.5207x; 1.0423x over previous
//
#include <hip/hip_runtime.h>
#include <hip/hip_bf16.h>
#include <cstdint>
#include <cstddef>

// ---------------------------------------------------------------------------
// RNNAttentionModel: embed -> 2-layer tanh RNN scan (MFMA-batched,
// wave-specialized) -> causal self-attention (bf16 MFMA GEMMs) -> FC(55)
// B=64 T=1024 E=64 H=128 V=55
// ---------------------------------------------------------------------------

typedef __attribute__((ext_vector_type(8))) short short8;   // 8 x bf16 frag
typedef __attribute__((ext_vector_type(4))) float f32x4;

__device__ __forceinline__ float bf2f(unsigned short u) {
    union { unsigned int i; float f; } c; c.i = ((unsigned int)u) << 16; return c.f;
}
__device__ __forceinline__ unsigned short f2bf(float f) {
    union { float f; unsigned int i; } c; c.f = f;
    unsigned int u = c.i;
    u += 0x7fffu + ((u >> 16) & 1u);   // RNE
    return (unsigned short)(u >> 16);
}
// v_cvt_pk_bf16_f32: pack two fp32 -> bf16x2 in one instruction
__device__ __forceinline__ unsigned int pk_bf16(float lo, float hi) {
    union { __hip_bfloat162 h2; unsigned int u; } c;
    c.h2 = __float22bfloat162_rn(make_float2(lo, hi));
    return c.u;
}
// tanh without the full-precision divide: v_rcp_f32 is ~1ulp, plenty for bf16
__device__ __forceinline__ float fast_tanh(float x) {
    float e = __expf(2.0f * x);
    return 1.0f - 2.0f * __builtin_amdgcn_rcpf(e + 1.0f);
}
// Raw workgroup barrier: waits LDS ops only; global loads/stores stay in
// flight (avoids the vmcnt(0) drain __syncthreads() would emit every step).
__device__ __forceinline__ void bar_lds() {
    asm volatile("s_waitcnt lgkmcnt(0)\n\ts_barrier" ::: "memory");
}
__device__ __forceinline__ short8 ld_a_bf16(const float* p) {
    const float4* q = (const float4*)p;
    float4 f0 = q[0], f1 = q[1];
    short8 r;
    r[0]=(short)f2bf(f0.x); r[1]=(short)f2bf(f0.y);
    r[2]=(short)f2bf(f0.z); r[3]=(short)f2bf(f0.w);
    r[4]=(short)f2bf(f1.x); r[5]=(short)f2bf(f1.y);
    r[6]=(short)f2bf(f1.z); r[7]=(short)f2bf(f1.w);
    return r;
}

// ---------------------------------------------------------------------------
// K0a: WE[v][i] = w_ih0[i,:] . emb[v,:] + b_ih0[i] + b_hh0[i]   (55 x 128)
// ---------------------------------------------------------------------------
__global__ __launch_bounds__(128)
void k_we(const float* __restrict__ emb, const float* __restrict__ w_ih0,
          const float* __restrict__ b_ih0, const float* __restrict__ b_hh0,
          float* __restrict__ WE)
{
    __shared__ float ev[64];
    const int i = threadIdx.x;
    const int v = blockIdx.x;
    if (i < 64) ev[i] = emb[v * 64 + i];
    __syncthreads();
    float s = b_ih0[i] + b_hh0[i];
    const float* wr = w_ih0 + i * 64;
#pragma unroll
    for (int k = 0; k < 64; ++k) s += wr[k] * ev[k];
    WE[v * 128 + i] = s;
}

// ---------------------------------------------------------------------------
// K0b: WEg[b][t][:] = WE[x[b][t]][:]   (pre-gathered layer-0 pre-activation)
// ---------------------------------------------------------------------------
__global__ __launch_bounds__(256)
void k_weg(const int* __restrict__ x, const float* __restrict__ WE,
           float* __restrict__ WEg)
{
    __shared__ int xv[32];
    const int tid = threadIdx.x;
    const int b   = blockIdx.y;
    const int t0  = blockIdx.x * 32;
    if (tid < 32) xv[tid] = x[b * 1024 + t0 + tid];
    __syncthreads();
#pragma unroll
    for (int it = 0; it < 4; ++it) {
        int tt = it * 8 + (tid >> 5);
        int c4 = tid & 31;
        float4 v = ((const float4*)(WE + xv[tt] * 128))[c4];
        ((float4*)(WEg + ((size_t)b * 1024 + t0 + tt) * 128))[c4] = v;
    }
}

// ---------------------------------------------------------------------------
// K1: MFMA-batched RNN scan, wave-specialized. 4 blocks x 16 batches,
// 512 threads = 4 A-waves (layer 0) + 4 B-waves (layer 1); each wave owns
// TWO 16-row M-tiles (stationary bf16 A-frags), so each B-fragment LDS read
// feeds 8 MFMAs (halves LDS BW vs 1 tile/wave). A-waves issue only global
// LOADS (WEg, depth-3 prefetch); B-waves only global STORES (h1) -> no
// in-order vmcnt chain where a load waits on slow stores. One barrier/step.
// ---------------------------------------------------------------------------
__global__ __launch_bounds__(512, 1)
void k_scan5(const float* __restrict__ WEg,
             const float* __restrict__ w_hh0,
             const float* __restrict__ w_ih1, const float* __restrict__ b_ih1,
             const float* __restrict__ w_hh1, const float* __restrict__ b_hh1,
             unsigned short* __restrict__ outs_bf)
{
    const int tid   = threadIdx.x;
    const int w     = tid >> 6;          // 0..3 A-waves, 4..7 B-waves
    const int lane  = tid & 63;
    const int quad  = lane >> 4;
    const int n     = lane & 15;         // batch col
    const int bbase = blockIdx.x * 16;

    __shared__ __align__(16) unsigned short h0buf[2][16][136];
    __shared__ __align__(16) unsigned short h1buf[2][16][136];

    if (w < 4) {
        // ================= A-waves: layer 0, M-tiles 2w, 2w+1 =============
        const int r0 = w * 32 + quad * 4;        // C rows tile0
        const int r1 = r0 + 16;                  // C rows tile1
        short8 a0[2][4];
#pragma unroll
        for (int r = 0; r < 2; ++r) {
            const size_t mrow = (size_t)(w * 32 + r * 16 + n) * 128;
#pragma unroll
            for (int ks = 0; ks < 4; ++ks)
                a0[r][ks] = ld_a_bf16(w_hh0 + mrow + ks * 32 + quad * 8);
        }
        const size_t wegB0 = (size_t)(bbase + n) * 131072 + r0;
        const size_t wegB1 = wegB0 + 16;
        {   // h0(0) = tanh(WEg[.][0])
            float4 p0 = *(const float4*)(WEg + wegB0);
            float4 p1 = *(const float4*)(WEg + wegB1);
            *(uint2*)&h0buf[0][n][r0] = make_uint2(
                pk_bf16(fast_tanh(p0.x), fast_tanh(p0.y)),
                pk_bf16(fast_tanh(p0.z), fast_tanh(p0.w)));
            *(uint2*)&h0buf[0][n][r1] = make_uint2(
                pk_bf16(fast_tanh(p1.x), fast_tanh(p1.y)),
                pk_bf16(fast_tanh(p1.z), fast_tanh(p1.w)));
        }
        float4 wA0 = *(const float4*)(WEg + wegB0 + 128);
        float4 wA1 = *(const float4*)(WEg + wegB1 + 128);
        float4 wB0 = *(const float4*)(WEg + wegB0 + 256);
        float4 wB1 = *(const float4*)(WEg + wegB1 + 256);
        float4 wC0 = *(const float4*)(WEg + wegB0 + 384);
        float4 wC1 = *(const float4*)(WEg + wegB1 + 384);
        __syncthreads();

        for (int t = 0; t < 1024; ++t) {
            const int p = t & 1;
            if (t < 1023) {
                const unsigned short* h0p = &h0buf[p][n][quad * 8];
                short8 bh[4];
#pragma unroll
                for (int ks = 0; ks < 4; ++ks)
                    bh[ks] = *(const short8*)(h0p + ks * 32);
                f32x4 c0 = (f32x4){wA0.x, wA0.y, wA0.z, wA0.w};
                f32x4 c1 = (f32x4){wA1.x, wA1.y, wA1.z, wA1.w};
#pragma unroll
                for (int ks = 0; ks < 4; ++ks) {
                    c0 = __builtin_amdgcn_mfma_f32_16x16x32_bf16(a0[0][ks], bh[ks], c0, 0,0,0);
                    c1 = __builtin_amdgcn_mfma_f32_16x16x32_bf16(a0[1][ks], bh[ks], c1, 0,0,0);
                }
                wA0 = wB0; wA1 = wB1; wB0 = wC0; wB1 = wC1;
                const size_t tpre = (size_t)((t + 4 < 1024) ? t + 4 : 1023) * 128;
                wC0 = *(const float4*)(WEg + wegB0 + tpre);
                wC1 = *(const float4*)(WEg + wegB1 + tpre);
                *(uint2*)&h0buf[p ^ 1][n][r0] = make_uint2(
                    pk_bf16(fast_tanh(c0[0]), fast_tanh(c0[1])),
                    pk_bf16(fast_tanh(c0[2]), fast_tanh(c0[3])));
                *(uint2*)&h0buf[p ^ 1][n][r1] = make_uint2(
                    pk_bf16(fast_tanh(c1[0]), fast_tanh(c1[1])),
                    pk_bf16(fast_tanh(c1[2]), fast_tanh(c1[3])));
            }
            bar_lds();
        }
    } else {
        // ================= B-waves: layer 1, M-tiles 2w', 2w'+1 ===========
        const int w2 = w - 4;
        const int r0 = w2 * 32 + quad * 4;
        const int r1 = r0 + 16;
        short8 a1[2][4], a2[2][4];
#pragma unroll
        for (int r = 0; r < 2; ++r) {
            const size_t mrow = (size_t)(w2 * 32 + r * 16 + n) * 128;
#pragma unroll
            for (int ks = 0; ks < 4; ++ks) {
                a1[r][ks] = ld_a_bf16(w_ih1 + mrow + ks * 32 + quad * 8);
                a2[r][ks] = ld_a_bf16(w_hh1 + mrow + ks * 32 + quad * 8);
            }
        }
        f32x4 b1i[2];
#pragma unroll
        for (int r = 0; r < 2; ++r)
#pragma unroll
            for (int j = 0; j < 4; ++j) {
                int row = w2 * 32 + r * 16 + quad * 4 + j;
                b1i[r][j] = b_ih1[row] + b_hh1[row];
            }
        // h1(-1) = 0
        *(uint2*)&h1buf[0][n][r0] = make_uint2(0u, 0u);
        *(uint2*)&h1buf[0][n][r1] = make_uint2(0u, 0u);
        unsigned short* outp0 = outs_bf + (size_t)(bbase + n) * 131072 + r0;
        unsigned short* outp1 = outp0 + 16;
        __syncthreads();

        for (int t = 0; t < 1024; ++t) {
            const int p = t & 1;
            const unsigned short* h0p = &h0buf[p][n][quad * 8];
            const unsigned short* h1p = &h1buf[p][n][quad * 8];
            short8 bh0[4], bh1[4];
#pragma unroll
            for (int ks = 0; ks < 4; ++ks) {
                bh0[ks] = *(const short8*)(h0p + ks * 32);
                bh1[ks] = *(const short8*)(h1p + ks * 32);
            }
            f32x4 c0 = b1i[0], c1 = b1i[1];
            f32x4 d0 = (f32x4){0.f,0.f,0.f,0.f}, d1 = (f32x4){0.f,0.f,0.f,0.f};
#pragma unroll
            for (int ks = 0; ks < 4; ++ks) {
                c0 = __builtin_amdgcn_mfma_f32_16x16x32_bf16(a1[0][ks], bh0[ks], c0, 0,0,0);
                c1 = __builtin_amdgcn_mfma_f32_16x16x32_bf16(a1[1][ks], bh0[ks], c1, 0,0,0);
                d0 = __builtin_amdgcn_mfma_f32_16x16x32_bf16(a2[0][ks], bh1[ks], d0, 0,0,0);
                d1 = __builtin_amdgcn_mfma_f32_16x16x32_bf16(a2[1][ks], bh1[ks], d1, 0,0,0);
            }
            uint2 o0 = make_uint2(
                pk_bf16(fast_tanh(c0[0] + d0[0]), fast_tanh(c0[1] + d0[1])),
                pk_bf16(fast_tanh(c0[2] + d0[2]), fast_tanh(c0[3] + d0[3])));
            uint2 o1 = make_uint2(
                pk_bf16(fast_tanh(c1[0] + d1[0]), fast_tanh(c1[1] + d1[1])),
                pk_bf16(fast_tanh(c1[2] + d1[2]), fast_tanh(c1[3] + d1[3])));
            *(uint2*)&h1buf[p ^ 1][n][r0] = o0;
            *(uint2*)&h1buf[p ^ 1][n][r1] = o1;
            *(uint2*)(outp0 + (size_t)t * 128) = o0;   // h1 -> global
            *(uint2*)(outp1 + (size_t)t * 128) = o1;
            bar_lds();
        }
    }
}

// ---------------------------------------------------------------------------
// K2: outs [b][t][h] -> outsT [b][h][t]  (LDS tile transpose)
// ---------------------------------------------------------------------------
__global__ __launch_bounds__(256)
void k_transpose(const unsigned short* __restrict__ outs_bf,
                 unsigned short* __restrict__ outsT)
{
    __shared__ unsigned short lt[128][130];
    const int tid = threadIdx.x;
    const int t0  = blockIdx.x * 128;
    const int b   = blockIdx.y;
    const unsigned int* src =
        (const unsigned int*)(outs_bf + ((size_t)b * 1024 + t0) * 128);
    for (int idx = tid; idx < 8192; idx += 256) {
        int tr = idx >> 6, h2 = idx & 63;
        unsigned int v = src[tr * 64 + h2];
        lt[tr][h2 * 2]     = (unsigned short)(v & 0xffffu);
        lt[tr][h2 * 2 + 1] = (unsigned short)(v >> 16);
    }
    __syncthreads();
    unsigned int* dst = (unsigned int*)(outsT + (size_t)b * 128 * 1024);
    for (int idx = tid; idx < 8192; idx += 256) {
        int h = idx >> 6, t2 = idx & 63;
        unsigned int v = (unsigned int)lt[t2 * 2][h] |
                         ((unsigned int)lt[t2 * 2 + 1][h] << 16);
        dst[h * 512 + (t0 >> 1) + t2] = v;
    }
}

// ---------------------------------------------------------------------------
// MFMA GEMM core conventions (16x16x32 bf16):
//   A frag: lane holds A[m=16*tile+(lane&15)][k = 8*(lane>>4) .. +7]
//   B frag: lane holds B[k][n] gathered as Brow[n=16*tile+(lane&15)][same k]
//   C/D   : col = lane&15, row = 4*(lane>>4) + reg
// LDS layout [row][k], 16B chunks XOR-swizzled: phys_k8 = k8 ^ (row & mask)
// ---------------------------------------------------------------------------

// K3: Q = outs @ attn_w.T + attn_b   (M = B*T, N = K = 128, one LDS pass)
__global__ __launch_bounds__(256, 2)
void k_qproj(const unsigned short* __restrict__ outs_bf,
             const float* __restrict__ attn_w, const float* __restrict__ attn_b,
             unsigned short* __restrict__ q_bf)
{
    __shared__ __align__(16) unsigned short lA[128 * 128];
    __shared__ __align__(16) unsigned short lB[128 * 128];
    const int tid   = threadIdx.x;
    const int mbase = blockIdx.x * 128;

    for (int c = tid; c < 2048; c += 256) {
        int row = c >> 4, k8 = c & 15;
        uint4 v = *(const uint4*)(outs_bf + ((size_t)(mbase + row)) * 128 + k8 * 8);
        *(uint4*)&lA[row * 128 + ((k8 ^ (row & 15)) << 3)] = v;
    }
    for (int c = tid; c < 2048; c += 256) {
        int row = c >> 4, k8 = c & 15;
        const float4* p = (const float4*)(attn_w + row * 128 + k8 * 8);
        float4 f0 = p[0], f1 = p[1];
        uint4 vv;
        vv.x = (unsigned int)f2bf(f0.x) | ((unsigned int)f2bf(f0.y) << 16);
        vv.y = (unsigned int)f2bf(f0.z) | ((unsigned int)f2bf(f0.w) << 16);
        vv.z = (unsigned int)f2bf(f1.x) | ((unsigned int)f2bf(f1.y) << 16);
        vv.w = (unsigned int)f2bf(f1.z) | ((unsigned int)f2bf(f1.w) << 16);
        *(uint4*)&lB[row * 128 + ((k8 ^ (row & 15)) << 3)] = vv;
    }
    __syncthreads();

    const int w = tid >> 6, lane = tid & 63, quad = lane >> 4, l16 = lane & 15;
    f32x4 acc[2][8];
#pragma unroll
    for (int r = 0; r < 2; ++r)
#pragma unroll
        for (int n = 0; n < 8; ++n) acc[r][n] = (f32x4){0.f, 0.f, 0.f, 0.f};

#pragma unroll
    for (int ks = 0; ks < 4; ++ks) {
        int k8 = ks * 4 + quad;
        short8 af[2];
#pragma unroll
        for (int r = 0; r < 2; ++r) {
            int row = w * 32 + r * 16 + l16;
            af[r] = *(const short8*)&lA[row * 128 + ((k8 ^ (row & 15)) << 3)];
        }
        short8 bfr[8];
#pragma unroll
        for (int n = 0; n < 8; ++n) {
            int col = n * 16 + l16;
            bfr[n] = *(const short8*)&lB[col * 128 + ((k8 ^ (col & 15)) << 3)];
        }
#pragma unroll
        for (int r = 0; r < 2; ++r)
#pragma unroll
            for (int n = 0; n < 8; ++n)
                acc[r][n] = __builtin_amdgcn_mfma_f32_16x16x32_bf16(
                    af[r], bfr[n], acc[r][n], 0, 0, 0);
    }
#pragma unroll
    for (int n = 0; n < 8; ++n) {
        int col = n * 16 + l16;
        float bias = attn_b[col];
#pragma unroll
        for (int r = 0; r < 2; ++r)
#pragma unroll
            for (int reg = 0; reg < 4; ++reg) {
                int row = w * 32 + r * 16 + quad * 4 + reg;
                q_bf[((size_t)(mbase + row)) * 128 + col] =
                    f2bf(acc[r][n][reg] + bias);
            }
    }
}

// K4: scores[b][q][k] = (Q[b][q] . outs[b][k]) / sqrt(H), causal tiles only
__global__ __launch_bounds__(256, 2)
void k_scores(const unsigned short* __restrict__ q_bf,
              const unsigned short* __restrict__ outs_bf,
              unsigned short* __restrict__ sc, int b0)
{
    const int kt = blockIdx.x, qt = blockIdx.y, bl = blockIdx.z;
    if (kt > qt) return;
    const int b = b0 + bl;

    __shared__ __align__(16) unsigned short lA[128 * 128];
    __shared__ __align__(16) unsigned short lB[128 * 128];
    const int tid = threadIdx.x;

    for (int c = tid; c < 2048; c += 256) {
        int row = c >> 4, k8 = c & 15;
        uint4 va = *(const uint4*)(q_bf +
            ((size_t)(b * 1024 + qt * 128 + row)) * 128 + k8 * 8);
        *(uint4*)&lA[row * 128 + ((k8 ^ (row & 15)) << 3)] = va;
        uint4 vb = *(const uint4*)(outs_bf +
            ((size_t)(b * 1024 + kt * 128 + row)) * 128 + k8 * 8);
        *(uint4*)&lB[row * 128 + ((k8 ^ (row & 15)) << 3)] = vb;
    }
    __syncthreads();

    const int w = tid >> 6, lane = tid & 63, quad = lane >> 4, l16 = lane & 15;
    f32x4 acc[2][8];
#pragma unroll
    for (int r = 0; r < 2; ++r)
#pragma unroll
        for (int n = 0; n < 8; ++n) acc[r][n] = (f32x4){0.f, 0.f, 0.f, 0.f};

#pragma unroll
    for (int ks = 0; ks < 4; ++ks) {
        int k8 = ks * 4 + quad;
        short8 af[2];
#pragma unroll
        for (int r = 0; r < 2; ++r) {
            int row = w * 32 + r * 16 + l16;
            af[r] = *(const short8*)&lA[row * 128 + ((k8 ^ (row & 15)) << 3)];
        }
        short8 bfr[8];
#pragma unroll
        for (int n = 0; n < 8; ++n) {
            int col = n * 16 + l16;
            bfr[n] = *(const short8*)&lB[col * 128 + ((k8 ^ (col & 15)) << 3)];
        }
#pragma unroll
        for (int r = 0; r < 2; ++r)
#pragma unroll
            for (int n = 0; n < 8; ++n)
                acc[r][n] = __builtin_amdgcn_mfma_f32_16x16x32_bf16(
                    af[r], bfr[n], acc[r][n], 0, 0, 0);
    }
    const float scale = 0.08838834764831845f;  // 1/sqrt(128)
#pragma unroll
    for (int n = 0; n < 8; ++n) {
        int col = n * 16 + l16;
#pragma unroll
        for (int r = 0; r < 2; ++r)
#pragma unroll
            for (int reg = 0; reg < 4; ++reg) {
                int row = w * 32 + r * 16 + quad * 4 + reg;
                sc[((size_t)(bl * 1024 + qt * 128 + row)) * 1024 + kt * 128 + col] =
                    f2bf(acc[r][n][reg] * scale);
            }
    }
}

// K5: causal softmax in place (bf16)
__global__ __launch_bounds__(256)
void k_softmax(unsigned short* __restrict__ sc)
{
    const int tid = threadIdx.x, w = tid >> 6, lane = tid & 63;
    const int r = blockIdx.x * 4 + w;           // row within chunk
    const int q = r & 1023;
    unsigned int* row = (unsigned int*)sc + (size_t)r * 512;
    const int nIter = (q >> 7) + 1;             // 128-element groups written

    float m = -1e30f, l = 0.f;
    for (int ii = 0; ii < nIter; ++ii) {
        int k2 = lane + (ii << 6);
        unsigned int u = row[k2];
        float a  = bf2f((unsigned short)(u & 0xffffu));
        float bq = bf2f((unsigned short)(u >> 16));
        float mt = fmaxf((2 * k2 <= q) ? a : -1e30f,
                         (2 * k2 + 1 <= q) ? bq : -1e30f);
        float mn = fmaxf(m, mt);
        float ea = (2 * k2     <= q) ? __expf(a  - mn) : 0.f;
        float eb = (2 * k2 + 1 <= q) ? __expf(bq - mn) : 0.f;
        l = l * __expf(m - mn) + ea + eb;
        m = mn;
    }
#pragma unroll
    for (int off = 1; off < 64; off <<= 1) {
        float m2 = __shfl_xor(m, off, 64);
        float l2 = __shfl_xor(l, off, 64);
        float mn = fmaxf(m, m2);
        l = l * __expf(m - mn) + l2 * __expf(m2 - mn);
        m = mn;
    }
    float inv = 1.0f / l;
    for (int ii = 0; ii < nIter; ++ii) {
        int k2 = lane + (ii << 6);
        unsigned int u = row[k2];
        float a  = bf2f((unsigned short)(u & 0xffffu));
        float bq = bf2f((unsigned short)(u >> 16));
        float pa = (2 * k2     <= q) ? __expf(a  - m) * inv : 0.f;
        float pb = (2 * k2 + 1 <= q) ? __expf(bq - m) * inv : 0.f;
        row[k2] = (unsigned int)f2bf(pa) | ((unsigned int)f2bf(pb) << 16);
    }
}

// K6: ctx[b][q][d] = P[b][q][s] @ V[s][d]  (V = outs, B-frag from outsT)
__global__ __launch_bounds__(256, 2)
void k_pv(const unsigned short* __restrict__ pr,
          const unsigned short* __restrict__ outsT,
          float* __restrict__ ctx, int b0)
{
    const int qt = blockIdx.x, bl = blockIdx.y;
    const int b = b0 + bl;
    __shared__ __align__(16) unsigned short lA[128 * 64];
    __shared__ __align__(16) unsigned short lB[128 * 64];
    const int tid = threadIdx.x;
    const int w = tid >> 6, lane = tid & 63, quad = lane >> 4, l16 = lane & 15;

    f32x4 acc[2][8];
#pragma unroll
    for (int r = 0; r < 2; ++r)
#pragma unroll
        for (int n = 0; n < 8; ++n) acc[r][n] = (f32x4){0.f, 0.f, 0.f, 0.f};

    const int stmax = 2 * qt + 1;
    for (int st = 0; st <= stmax; ++st) {
        __syncthreads();
        for (int c = tid; c < 1024; c += 256) {
            int row = c >> 3, k8 = c & 7;
            uint4 va = *(const uint4*)(pr +
                ((size_t)(bl * 1024 + qt * 128 + row)) * 1024 + st * 64 + k8 * 8);
            *(uint4*)&lA[row * 64 + ((k8 ^ (row & 7)) << 3)] = va;
            uint4 vb = *(const uint4*)(outsT +
                ((size_t)(b * 128 + row)) * 1024 + st * 64 + k8 * 8);
            *(uint4*)&lB[row * 64 + ((k8 ^ (row & 7)) << 3)] = vb;
        }
        __syncthreads();
#pragma unroll
        for (int ks = 0; ks < 2; ++ks) {
            int k8 = ks * 4 + quad;
            short8 af[2];
#pragma unroll
            for (int r = 0; r < 2; ++r) {
                int row = w * 32 + r * 16 + l16;
                af[r] = *(const short8*)&lA[row * 64 + ((k8 ^ (row & 7)) << 3)];
            }
            short8 bfr[8];
#pragma unroll
            for (int n = 0; n < 8; ++n) {
                int col = n * 16 + l16;
                bfr[n] = *(const short8*)&lB[col * 64 + ((k8 ^ (col & 7)) << 3)];
            }
#pragma unroll
            for (int r = 0; r < 2; ++r)
#pragma unroll
                for (int n = 0; n < 8; ++n)
                    acc[r][n] = __builtin_amdgcn_mfma_f32_16x16x32_bf16(
                        af[r], bfr[n], acc[r][n], 0, 0, 0);
        }
    }
#pragma unroll
    for (int n = 0; n < 8; ++n) {
        int col = n * 16 + l16;
#pragma unroll
        for (int r = 0; r < 2; ++r)
#pragma unroll
            for (int reg = 0; reg < 4; ++reg) {
                int row = w * 32 + r * 16 + quad * 4 + reg;
                ctx[((size_t)(b * 1024) + qt * 128 + row) * 128 + col] =
                    acc[r][n][reg];
            }
    }
}

// K7: logits = [outs | ctx] @ fc_w.T + fc_b   (V=55, K=256)
__global__ __launch_bounds__(256, 2)
void k_fc(const unsigned short* __restrict__ outs_bf,
          const float* __restrict__ ctx,
          const float* __restrict__ fc_w, const float* __restrict__ fc_b,
          float* __restrict__ out)
{
    __shared__ float lw[55 * 257];
    __shared__ float comb[256];
    __shared__ float part[256];
    const int tid = threadIdx.x;
    const int c = tid >> 6, v = tid & 63;

    for (int idx = tid; idx < 55 * 256; idx += 256) {
        int rr = idx >> 8, cc = idx & 255;
        lw[rr * 257 + cc] = fc_w[idx];
    }
    __syncthreads();

    const int t0 = blockIdx.x * 64;
    for (int t = 0; t < 64; ++t) {
        size_t bt = (size_t)(t0 + t);
        if (tid < 128) comb[tid] = bf2f(outs_bf[bt * 128 + tid]);
        else           comb[tid] = ctx[bt * 128 + (tid - 128)];
        __syncthreads();
        float p0 = 0.f, p1 = 0.f, p2 = 0.f, p3 = 0.f;
        if (v < 55) {
            const float* wr = lw + v * 257 + c * 64;
            const float* cb = comb + c * 64;
#pragma unroll
            for (int j = 0; j < 16; ++j) {
                p0 += wr[4*j]   * cb[4*j];
                p1 += wr[4*j+1] * cb[4*j+1];
                p2 += wr[4*j+2] * cb[4*j+2];
                p3 += wr[4*j+3] * cb[4*j+3];
            }
        }
        part[tid] = (p0 + p1) + (p2 + p3);
        __syncthreads();
        if (tid < 55) {
            out[bt * 55 + tid] = fc_b[tid] + part[tid] + part[64 + tid] +
                                 part[128 + tid] + part[192 + tid];
        }
        __syncthreads();
    }
}

// ---------------------------------------------------------------------------
extern "C" void kernel_launch(void* const* d_in, const int* in_sizes, int n_in,
                              void* d_out, int out_size, void* d_ws, size_t ws_size,
                              hipStream_t stream)
{
    const int*   x      = (const int*)d_in[0];
    const float* emb    = (const float*)d_in[1];
    const float* w_ih0  = (const float*)d_in[2];
    const float* b_ih0  = (const float*)d_in[3];
    const float* w_hh0  = (const float*)d_in[4];
    const float* b_hh0  = (const float*)d_in[5];
    const float* w_ih1  = (const float*)d_in[6];
    const float* b_ih1  = (const float*)d_in[7];
    const float* w_hh1  = (const float*)d_in[8];
    const float* b_hh1  = (const float*)d_in[9];
    const float* attn_w = (const float*)d_in[10];
    const float* attn_b = (const float*)d_in[11];
    const float* fc_w   = (const float*)d_in[12];
    const float* fc_b   = (const float*)d_in[13];
    float* out = (float*)d_out;

    char* ws = (char*)d_ws;
    unsigned short* outs_bf = (unsigned short*)(ws);                        // 16 MiB
    unsigned short* outsT   = (unsigned short*)(ws + ((size_t)16 << 20));   // 16 MiB
    unsigned short* q_bf    = (unsigned short*)(ws + ((size_t)32 << 20));   // 16 MiB
    float*          ctx     = (float*)         (ws + ((size_t)48 << 20));   // 32 MiB
    float*          WEp     = (float*)         (ws + ((size_t)80 << 20));   // 28 KiB
    float*          WEg     = (float*)         (ws + ((size_t)81 << 20));   // 32 MiB
    unsigned short* sc      = (unsigned short*)(ws + ((size_t)113 << 20));  // CB*2 MiB

    size_t fixed = (size_t)113 << 20;
    size_t avail = (ws_size > fixed) ? (ws_size - fixed) : 0;
    int CB = (int)(avail / ((size_t)2 << 20));
    if (CB < 1)  CB = 1;
    if (CB > 64) CB = 64;

    k_we<<<dim3(55), dim3(128), 0, stream>>>(emb, w_ih0, b_ih0, b_hh0, WEp);
    k_weg<<<dim3(32, 64), dim3(256), 0, stream>>>(x, WEp, WEg);
    k_scan5<<<dim3(4), dim3(512), 0, stream>>>(
        WEg, w_hh0, w_ih1, b_ih1, w_hh1, b_hh1, outs_bf);
    k_transpose<<<dim3(8, 64), dim3(256), 0, stream>>>(outs_bf, outsT);
    k_qproj<<<dim3(512), dim3(256), 0, stream>>>(outs_bf, attn_w, attn_b, q_bf);

    for (int b0 = 0; b0 < 64; b0 += CB) {
        int nb = 64 - b0; if (nb > CB) nb = CB;
        k_scores <<<dim3(8, 8, nb), dim3(256), 0, stream>>>(q_bf, outs_bf, sc, b0);
        k_softmax<<<dim3(nb * 256), dim3(256), 0, stream>>>(sc);
        k_pv     <<<dim3(8, nb),   dim3(256), 0, stream>>>(sc, outsT, ctx, b0);
    }
    k_fc<<<dim3(1024), dim3(256), 0, stream>>>(outs_bf, ctx, fc_w, fc_b, out);
}

// Round 6
// 968.511 us; speedup vs baseline: 1.5212x; 1.0004x over previous
//
#include <hip/hip_runtime.h>
#include <hip/hip_bf16.h>
#include <cstdint>
#include <cstddef>

// ---------------------------------------------------------------------------
// RNNAttentionModel: embed -> 2-layer tanh RNN scan (MFMA-batched,
// wave-specialized) -> fused flash causal attention -> FC(55)
// B=64 T=1024 E=64 H=128 V=55
// ---------------------------------------------------------------------------

typedef __attribute__((ext_vector_type(8))) short short8;   // 8 x bf16 frag
typedef __attribute__((ext_vector_type(4))) float f32x4;

__device__ __forceinline__ float bf2f(unsigned short u) {
    union { unsigned int i; float f; } c; c.i = ((unsigned int)u) << 16; return c.f;
}
__device__ __forceinline__ unsigned short f2bf(float f) {
    union { float f; unsigned int i; } c; c.f = f;
    unsigned int u = c.i;
    u += 0x7fffu + ((u >> 16) & 1u);   // RNE
    return (unsigned short)(u >> 16);
}
// v_cvt_pk_bf16_f32: pack two fp32 -> bf16x2 in one instruction
__device__ __forceinline__ unsigned int pk_bf16(float lo, float hi) {
    union { __hip_bfloat162 h2; unsigned int u; } c;
    c.h2 = __float22bfloat162_rn(make_float2(lo, hi));
    return c.u;
}
// tanh without the full-precision divide: v_rcp_f32 is ~1ulp, plenty for bf16
__device__ __forceinline__ float fast_tanh(float x) {
    float e = __expf(2.0f * x);
    return 1.0f - 2.0f * __builtin_amdgcn_rcpf(e + 1.0f);
}
// Raw workgroup barrier: waits LDS ops only; global loads/stores stay in
// flight (avoids the vmcnt(0) drain __syncthreads() would emit every step).
__device__ __forceinline__ void bar_lds() {
    asm volatile("s_waitcnt lgkmcnt(0)\n\ts_barrier" ::: "memory");
}
__device__ __forceinline__ short8 ld_a_bf16(const float* p) {
    const float4* q = (const float4*)p;
    float4 f0 = q[0], f1 = q[1];
    short8 r;
    r[0]=(short)f2bf(f0.x); r[1]=(short)f2bf(f0.y);
    r[2]=(short)f2bf(f0.z); r[3]=(short)f2bf(f0.w);
    r[4]=(short)f2bf(f1.x); r[5]=(short)f2bf(f1.y);
    r[6]=(short)f2bf(f1.z); r[7]=(short)f2bf(f1.w);
    return r;
}

// ---------------------------------------------------------------------------
// K0a: WE[v][i] = w_ih0[i,:] . emb[v,:] + b_ih0[i] + b_hh0[i]   (55 x 128)
// ---------------------------------------------------------------------------
__global__ __launch_bounds__(128)
void k_we(const float* __restrict__ emb, const float* __restrict__ w_ih0,
          const float* __restrict__ b_ih0, const float* __restrict__ b_hh0,
          float* __restrict__ WE)
{
    __shared__ float ev[64];
    const int i = threadIdx.x;
    const int v = blockIdx.x;
    if (i < 64) ev[i] = emb[v * 64 + i];
    __syncthreads();
    float s = b_ih0[i] + b_hh0[i];
    const float* wr = w_ih0 + i * 64;
#pragma unroll
    for (int k = 0; k < 64; ++k) s += wr[k] * ev[k];
    WE[v * 128 + i] = s;
}

// ---------------------------------------------------------------------------
// K0b: WEg[b][t][:] = WE[x[b][t]][:]   (pre-gathered layer-0 pre-activation)
// ---------------------------------------------------------------------------
__global__ __launch_bounds__(256)
void k_weg(const int* __restrict__ x, const float* __restrict__ WE,
           float* __restrict__ WEg)
{
    __shared__ int xv[32];
    const int tid = threadIdx.x;
    const int b   = blockIdx.y;
    const int t0  = blockIdx.x * 32;
    if (tid < 32) xv[tid] = x[b * 1024 + t0 + tid];
    __syncthreads();
#pragma unroll
    for (int it = 0; it < 4; ++it) {
        int tt = it * 8 + (tid >> 5);
        int c4 = tid & 31;
        float4 v = ((const float4*)(WE + xv[tt] * 128))[c4];
        ((float4*)(WEg + ((size_t)b * 1024 + t0 + tt) * 128))[c4] = v;
    }
}

// ---------------------------------------------------------------------------
// K1: MFMA-batched RNN scan, wave-specialized (unchanged from R5).
// ---------------------------------------------------------------------------
__global__ __launch_bounds__(512, 1)
void k_scan5(const float* __restrict__ WEg,
             const float* __restrict__ w_hh0,
             const float* __restrict__ w_ih1, const float* __restrict__ b_ih1,
             const float* __restrict__ w_hh1, const float* __restrict__ b_hh1,
             unsigned short* __restrict__ outs_bf)
{
    const int tid   = threadIdx.x;
    const int w     = tid >> 6;          // 0..3 A-waves, 4..7 B-waves
    const int lane  = tid & 63;
    const int quad  = lane >> 4;
    const int n     = lane & 15;         // batch col
    const int bbase = blockIdx.x * 16;

    __shared__ __align__(16) unsigned short h0buf[2][16][136];
    __shared__ __align__(16) unsigned short h1buf[2][16][136];

    if (w < 4) {
        // ================= A-waves: layer 0, M-tiles 2w, 2w+1 =============
        const int r0 = w * 32 + quad * 4;        // C rows tile0
        const int r1 = r0 + 16;                  // C rows tile1
        short8 a0[2][4];
#pragma unroll
        for (int r = 0; r < 2; ++r) {
            const size_t mrow = (size_t)(w * 32 + r * 16 + n) * 128;
#pragma unroll
            for (int ks = 0; ks < 4; ++ks)
                a0[r][ks] = ld_a_bf16(w_hh0 + mrow + ks * 32 + quad * 8);
        }
        const size_t wegB0 = (size_t)(bbase + n) * 131072 + r0;
        const size_t wegB1 = wegB0 + 16;
        {   // h0(0) = tanh(WEg[.][0])
            float4 p0 = *(const float4*)(WEg + wegB0);
            float4 p1 = *(const float4*)(WEg + wegB1);
            *(uint2*)&h0buf[0][n][r0] = make_uint2(
                pk_bf16(fast_tanh(p0.x), fast_tanh(p0.y)),
                pk_bf16(fast_tanh(p0.z), fast_tanh(p0.w)));
            *(uint2*)&h0buf[0][n][r1] = make_uint2(
                pk_bf16(fast_tanh(p1.x), fast_tanh(p1.y)),
                pk_bf16(fast_tanh(p1.z), fast_tanh(p1.w)));
        }
        float4 wA0 = *(const float4*)(WEg + wegB0 + 128);
        float4 wA1 = *(const float4*)(WEg + wegB1 + 128);
        float4 wB0 = *(const float4*)(WEg + wegB0 + 256);
        float4 wB1 = *(const float4*)(WEg + wegB1 + 256);
        float4 wC0 = *(const float4*)(WEg + wegB0 + 384);
        float4 wC1 = *(const float4*)(WEg + wegB1 + 384);
        __syncthreads();

        for (int t = 0; t < 1024; ++t) {
            const int p = t & 1;
            if (t < 1023) {
                const unsigned short* h0p = &h0buf[p][n][quad * 8];
                short8 bh[4];
#pragma unroll
                for (int ks = 0; ks < 4; ++ks)
                    bh[ks] = *(const short8*)(h0p + ks * 32);
                f32x4 c0 = (f32x4){wA0.x, wA0.y, wA0.z, wA0.w};
                f32x4 c1 = (f32x4){wA1.x, wA1.y, wA1.z, wA1.w};
#pragma unroll
                for (int ks = 0; ks < 4; ++ks) {
                    c0 = __builtin_amdgcn_mfma_f32_16x16x32_bf16(a0[0][ks], bh[ks], c0, 0,0,0);
                    c1 = __builtin_amdgcn_mfma_f32_16x16x32_bf16(a0[1][ks], bh[ks], c1, 0,0,0);
                }
                wA0 = wB0; wA1 = wB1; wB0 = wC0; wB1 = wC1;
                const size_t tpre = (size_t)((t + 4 < 1024) ? t + 4 : 1023) * 128;
                wC0 = *(const float4*)(WEg + wegB0 + tpre);
                wC1 = *(const float4*)(WEg + wegB1 + tpre);
                *(uint2*)&h0buf[p ^ 1][n][r0] = make_uint2(
                    pk_bf16(fast_tanh(c0[0]), fast_tanh(c0[1])),
                    pk_bf16(fast_tanh(c0[2]), fast_tanh(c0[3])));
                *(uint2*)&h0buf[p ^ 1][n][r1] = make_uint2(
                    pk_bf16(fast_tanh(c1[0]), fast_tanh(c1[1])),
                    pk_bf16(fast_tanh(c1[2]), fast_tanh(c1[3])));
            }
            bar_lds();
        }
    } else {
        // ================= B-waves: layer 1, M-tiles 2w', 2w'+1 ===========
        const int w2 = w - 4;
        const int r0 = w2 * 32 + quad * 4;
        const int r1 = r0 + 16;
        short8 a1[2][4], a2[2][4];
#pragma unroll
        for (int r = 0; r < 2; ++r) {
            const size_t mrow = (size_t)(w2 * 32 + r * 16 + n) * 128;
#pragma unroll
            for (int ks = 0; ks < 4; ++ks) {
                a1[r][ks] = ld_a_bf16(w_ih1 + mrow + ks * 32 + quad * 8);
                a2[r][ks] = ld_a_bf16(w_hh1 + mrow + ks * 32 + quad * 8);
            }
        }
        f32x4 b1i[2];
#pragma unroll
        for (int r = 0; r < 2; ++r)
#pragma unroll
            for (int j = 0; j < 4; ++j) {
                int row = w2 * 32 + r * 16 + quad * 4 + j;
                b1i[r][j] = b_ih1[row] + b_hh1[row];
            }
        // h1(-1) = 0
        *(uint2*)&h1buf[0][n][r0] = make_uint2(0u, 0u);
        *(uint2*)&h1buf[0][n][r1] = make_uint2(0u, 0u);
        unsigned short* outp0 = outs_bf + (size_t)(bbase + n) * 131072 + r0;
        unsigned short* outp1 = outp0 + 16;
        __syncthreads();

        for (int t = 0; t < 1024; ++t) {
            const int p = t & 1;
            const unsigned short* h0p = &h0buf[p][n][quad * 8];
            const unsigned short* h1p = &h1buf[p][n][quad * 8];
            short8 bh0[4], bh1[4];
#pragma unroll
            for (int ks = 0; ks < 4; ++ks) {
                bh0[ks] = *(const short8*)(h0p + ks * 32);
                bh1[ks] = *(const short8*)(h1p + ks * 32);
            }
            f32x4 c0 = b1i[0], c1 = b1i[1];
            f32x4 d0 = (f32x4){0.f,0.f,0.f,0.f}, d1 = (f32x4){0.f,0.f,0.f,0.f};
#pragma unroll
            for (int ks = 0; ks < 4; ++ks) {
                c0 = __builtin_amdgcn_mfma_f32_16x16x32_bf16(a1[0][ks], bh0[ks], c0, 0,0,0);
                c1 = __builtin_amdgcn_mfma_f32_16x16x32_bf16(a1[1][ks], bh0[ks], c1, 0,0,0);
                d0 = __builtin_amdgcn_mfma_f32_16x16x32_bf16(a2[0][ks], bh1[ks], d0, 0,0,0);
                d1 = __builtin_amdgcn_mfma_f32_16x16x32_bf16(a2[1][ks], bh1[ks], d1, 0,0,0);
            }
            uint2 o0 = make_uint2(
                pk_bf16(fast_tanh(c0[0] + d0[0]), fast_tanh(c0[1] + d0[1])),
                pk_bf16(fast_tanh(c0[2] + d0[2]), fast_tanh(c0[3] + d0[3])));
            uint2 o1 = make_uint2(
                pk_bf16(fast_tanh(c1[0] + d1[0]), fast_tanh(c1[1] + d1[1])),
                pk_bf16(fast_tanh(c1[2] + d1[2]), fast_tanh(c1[3] + d1[3])));
            *(uint2*)&h1buf[p ^ 1][n][r0] = o0;
            *(uint2*)&h1buf[p ^ 1][n][r1] = o1;
            *(uint2*)(outp0 + (size_t)t * 128) = o0;   // h1 -> global
            *(uint2*)(outp1 + (size_t)t * 128) = o1;
            bar_lds();
        }
    }
}

// ---------------------------------------------------------------------------
// K2: outs [b][t][h] -> outsT [b][h][t]  (LDS tile transpose)
// ---------------------------------------------------------------------------
__global__ __launch_bounds__(256)
void k_transpose(const unsigned short* __restrict__ outs_bf,
                 unsigned short* __restrict__ outsT)
{
    __shared__ unsigned short lt[128][130];
    const int tid = threadIdx.x;
    const int t0  = blockIdx.x * 128;
    const int b   = blockIdx.y;
    const unsigned int* src =
        (const unsigned int*)(outs_bf + ((size_t)b * 1024 + t0) * 128);
    for (int idx = tid; idx < 8192; idx += 256) {
        int tr = idx >> 6, h2 = idx & 63;
        unsigned int v = src[tr * 64 + h2];
        lt[tr][h2 * 2]     = (unsigned short)(v & 0xffffu);
        lt[tr][h2 * 2 + 1] = (unsigned short)(v >> 16);
    }
    __syncthreads();
    unsigned int* dst = (unsigned int*)(outsT + (size_t)b * 128 * 1024);
    for (int idx = tid; idx < 8192; idx += 256) {
        int h = idx >> 6, t2 = idx & 63;
        unsigned int v = (unsigned int)lt[t2 * 2][h] |
                         ((unsigned int)lt[t2 * 2 + 1][h] << 16);
        dst[h * 512 + (t0 >> 1) + t2] = v;
    }
}

// ---------------------------------------------------------------------------
// K3: Q = outs @ attn_w.T + attn_b   (M = B*T, N = K = 128, one LDS pass)
// ---------------------------------------------------------------------------
__global__ __launch_bounds__(256, 2)
void k_qproj(const unsigned short* __restrict__ outs_bf,
             const float* __restrict__ attn_w, const float* __restrict__ attn_b,
             unsigned short* __restrict__ q_bf)
{
    __shared__ __align__(16) unsigned short lA[128 * 128];
    __shared__ __align__(16) unsigned short lB[128 * 128];
    const int tid   = threadIdx.x;
    const int mbase = blockIdx.x * 128;

    for (int c = tid; c < 2048; c += 256) {
        int row = c >> 4, k8 = c & 15;
        uint4 v = *(const uint4*)(outs_bf + ((size_t)(mbase + row)) * 128 + k8 * 8);
        *(uint4*)&lA[row * 128 + ((k8 ^ (row & 15)) << 3)] = v;
    }
    for (int c = tid; c < 2048; c += 256) {
        int row = c >> 4, k8 = c & 15;
        const float4* p = (const float4*)(attn_w + row * 128 + k8 * 8);
        float4 f0 = p[0], f1 = p[1];
        uint4 vv;
        vv.x = (unsigned int)f2bf(f0.x) | ((unsigned int)f2bf(f0.y) << 16);
        vv.y = (unsigned int)f2bf(f0.z) | ((unsigned int)f2bf(f0.w) << 16);
        vv.z = (unsigned int)f2bf(f1.x) | ((unsigned int)f2bf(f1.y) << 16);
        vv.w = (unsigned int)f2bf(f1.z) | ((unsigned int)f2bf(f1.w) << 16);
        *(uint4*)&lB[row * 128 + ((k8 ^ (row & 15)) << 3)] = vv;
    }
    __syncthreads();

    const int w = tid >> 6, lane = tid & 63, quad = lane >> 4, l16 = lane & 15;
    f32x4 acc[2][8];
#pragma unroll
    for (int r = 0; r < 2; ++r)
#pragma unroll
        for (int n = 0; n < 8; ++n) acc[r][n] = (f32x4){0.f, 0.f, 0.f, 0.f};

#pragma unroll
    for (int ks = 0; ks < 4; ++ks) {
        int k8 = ks * 4 + quad;
        short8 af[2];
#pragma unroll
        for (int r = 0; r < 2; ++r) {
            int row = w * 32 + r * 16 + l16;
            af[r] = *(const short8*)&lA[row * 128 + ((k8 ^ (row & 15)) << 3)];
        }
        short8 bfr[8];
#pragma unroll
        for (int n = 0; n < 8; ++n) {
            int col = n * 16 + l16;
            bfr[n] = *(const short8*)&lB[col * 128 + ((k8 ^ (col & 15)) << 3)];
        }
#pragma unroll
        for (int r = 0; r < 2; ++r)
#pragma unroll
            for (int n = 0; n < 8; ++n)
                acc[r][n] = __builtin_amdgcn_mfma_f32_16x16x32_bf16(
                    af[r], bfr[n], acc[r][n], 0, 0, 0);
    }
#pragma unroll
    for (int n = 0; n < 8; ++n) {
        int col = n * 16 + l16;
        float bias = attn_b[col];
#pragma unroll
        for (int r = 0; r < 2; ++r)
#pragma unroll
            for (int reg = 0; reg < 4; ++reg) {
                int row = w * 32 + r * 16 + quad * 4 + reg;
                q_bf[((size_t)(mbase + row)) * 128 + col] =
                    f2bf(acc[r][n][reg] + bias);
            }
    }
}

// ---------------------------------------------------------------------------
// K4: fused flash causal attention, transposed orientation, barrier-free.
// One wave per 32 q-rows. S^T = K·Q^T (C col = q), so softmax over kr is
// in-lane (32 vals) + shfl_xor(16,32) across quads. P^T round-trips through
// wave-private LDS (no __syncthreads). PV as O^T = V^T·P^T; d-contiguous
// float4 ctx stores. Online softmax state (m,l) = 2 scalars/lane.
// ---------------------------------------------------------------------------
__global__ __launch_bounds__(256, 2)
void k_attn(const unsigned short* __restrict__ q_bf,
            const unsigned short* __restrict__ outs_bf,
            const unsigned short* __restrict__ outsT,
            float* __restrict__ ctx)
{
    __shared__ __align__(16) unsigned short lP[4][32][136];
    const int tid  = threadIdx.x;
    const int w    = tid >> 6;
    const int lane = tid & 63;
    const int quad = lane >> 4;
    const int n    = lane & 15;
    const int b    = blockIdx.y;
    const int g    = blockIdx.x * 4 + w;       // 32-row q strip, 0..31
    const int q0   = g * 32;
    const int kdiag = g >> 2;
    const float c = 0.08838834764831845f;      // 1/sqrt(128)

    // stationary Q B-frags: lane holds Q[q=q0+16*nt2+n][h=32ks+8quad..+7]
    short8 qf[2][4];
#pragma unroll
    for (int nt2 = 0; nt2 < 2; ++nt2)
#pragma unroll
        for (int ks = 0; ks < 4; ++ks)
            qf[nt2][ks] = *(const short8*)(q_bf +
                ((size_t)b * 1024 + q0 + nt2 * 16 + n) * 128 + ks * 32 + quad * 8);

    f32x4 accO[8][2];                          // O^T [d-tile][q-tile]
#pragma unroll
    for (int dt = 0; dt < 8; ++dt)
#pragma unroll
        for (int nt2 = 0; nt2 < 2; ++nt2)
            accO[dt][nt2] = (f32x4){0.f, 0.f, 0.f, 0.f};
    float m[2] = {-1e30f, -1e30f};
    float l[2] = {0.f, 0.f};

    for (int kt = 0; kt <= kdiag; ++kt) {
        // ---- S^T = K · Q^T ----
        f32x4 accS[8][2];
#pragma unroll
        for (int mt = 0; mt < 8; ++mt) {
            short8 af[4];
#pragma unroll
            for (int ks = 0; ks < 4; ++ks)
                af[ks] = *(const short8*)(outs_bf +
                    ((size_t)b * 1024 + kt * 128 + mt * 16 + n) * 128 +
                    ks * 32 + quad * 8);
            f32x4 s0 = (f32x4){0.f,0.f,0.f,0.f};
            f32x4 s1 = (f32x4){0.f,0.f,0.f,0.f};
#pragma unroll
            for (int ks = 0; ks < 4; ++ks) {
                s0 = __builtin_amdgcn_mfma_f32_16x16x32_bf16(af[ks], qf[0][ks], s0, 0,0,0);
                s1 = __builtin_amdgcn_mfma_f32_16x16x32_bf16(af[ks], qf[1][ks], s1, 0,0,0);
            }
            accS[mt][0] = s0; accS[mt][1] = s1;
        }
        // ---- causal mask on the diagonal tile ----
        if (kt == kdiag) {
#pragma unroll
            for (int mt = 0; mt < 8; ++mt)
#pragma unroll
                for (int nt2 = 0; nt2 < 2; ++nt2) {
                    int qq = q0 + nt2 * 16 + n;
#pragma unroll
                    for (int j = 0; j < 4; ++j) {
                        int kr = kt * 128 + mt * 16 + quad * 4 + j;
                        if (kr > qq) accS[mt][nt2][j] = -1e30f;
                    }
                }
        }
        // ---- online softmax (per q-tile nt2) ----
        float alpha[2];
#pragma unroll
        for (int nt2 = 0; nt2 < 2; ++nt2) {
            float tmax = accS[0][nt2][0];
#pragma unroll
            for (int mt = 0; mt < 8; ++mt)
#pragma unroll
                for (int j = 0; j < 4; ++j)
                    tmax = fmaxf(tmax, accS[mt][nt2][j]);
            tmax = fmaxf(tmax, __shfl_xor(tmax, 16));
            tmax = fmaxf(tmax, __shfl_xor(tmax, 32));
            float nm = fmaxf(m[nt2], tmax);
            alpha[nt2] = __expf((m[nt2] - nm) * c);
            float s = 0.f;
#pragma unroll
            for (int mt = 0; mt < 8; ++mt)
#pragma unroll
                for (int j = 0; j < 4; ++j) {
                    float p = __expf((accS[mt][nt2][j] - nm) * c);
                    accS[mt][nt2][j] = p;
                    s += p;
                }
            s += __shfl_xor(s, 16);
            s += __shfl_xor(s, 32);
            l[nt2] = l[nt2] * alpha[nt2] + s;
            m[nt2] = nm;
        }
        // ---- P^T -> wave-private LDS (bf16); no barrier needed ----
#pragma unroll
        for (int mt = 0; mt < 8; ++mt)
#pragma unroll
            for (int nt2 = 0; nt2 < 2; ++nt2) {
                uint2 pv = make_uint2(
                    pk_bf16(accS[mt][nt2][0], accS[mt][nt2][1]),
                    pk_bf16(accS[mt][nt2][2], accS[mt][nt2][3]));
                *(uint2*)&lP[w][nt2 * 16 + n][mt * 16 + quad * 4] = pv;
            }
        // ---- rescale O by alpha ----
#pragma unroll
        for (int dt = 0; dt < 8; ++dt)
#pragma unroll
            for (int nt2 = 0; nt2 < 2; ++nt2)
#pragma unroll
                for (int j = 0; j < 4; ++j)
                    accO[dt][nt2][j] *= alpha[nt2];
        // ---- P^T B-frags from LDS (compiler orders vs the writes above) ----
        short8 pf[2][4];
#pragma unroll
        for (int nt2 = 0; nt2 < 2; ++nt2)
#pragma unroll
            for (int ks = 0; ks < 4; ++ks)
                pf[nt2][ks] = *(const short8*)
                    &lP[w][nt2 * 16 + n][ks * 32 + quad * 8];
        // ---- O^T += V^T · P^T ----
#pragma unroll
        for (int dt = 0; dt < 8; ++dt) {
            short8 vf[4];
#pragma unroll
            for (int ks = 0; ks < 4; ++ks)
                vf[ks] = *(const short8*)(outsT +
                    (size_t)b * 131072 + (size_t)(dt * 16 + n) * 1024 +
                    kt * 128 + ks * 32 + quad * 8);
#pragma unroll
            for (int ks = 0; ks < 4; ++ks) {
                accO[dt][0] = __builtin_amdgcn_mfma_f32_16x16x32_bf16(vf[ks], pf[0][ks], accO[dt][0], 0,0,0);
                accO[dt][1] = __builtin_amdgcn_mfma_f32_16x16x32_bf16(vf[ks], pf[1][ks], accO[dt][1], 0,0,0);
            }
        }
    }
    // ---- epilogue: normalize and store ctx[b][q][d] (d-contiguous) ----
#pragma unroll
    for (int nt2 = 0; nt2 < 2; ++nt2) {
        float inv = __builtin_amdgcn_rcpf(l[nt2]);
        size_t rowbase = ((size_t)b * 1024 + q0 + nt2 * 16 + n) * 128;
#pragma unroll
        for (int dt = 0; dt < 8; ++dt) {
            float4 o = make_float4(accO[dt][nt2][0] * inv, accO[dt][nt2][1] * inv,
                                   accO[dt][nt2][2] * inv, accO[dt][nt2][3] * inv);
            *(float4*)(ctx + rowbase + dt * 16 + quad * 4) = o;
        }
    }
}

// ---------------------------------------------------------------------------
// K7: logits = [outs | ctx] @ fc_w.T + fc_b   (V=55, K=256)
// ---------------------------------------------------------------------------
__global__ __launch_bounds__(256, 2)
void k_fc(const unsigned short* __restrict__ outs_bf,
          const float* __restrict__ ctx,
          const float* __restrict__ fc_w, const float* __restrict__ fc_b,
          float* __restrict__ out)
{
    __shared__ float lw[55 * 257];
    __shared__ float comb[256];
    __shared__ float part[256];
    const int tid = threadIdx.x;
    const int c = tid >> 6, v = tid & 63;

    for (int idx = tid; idx < 55 * 256; idx += 256) {
        int rr = idx >> 8, cc = idx & 255;
        lw[rr * 257 + cc] = fc_w[idx];
    }
    __syncthreads();

    const int t0 = blockIdx.x * 64;
    for (int t = 0; t < 64; ++t) {
        size_t bt = (size_t)(t0 + t);
        if (tid < 128) comb[tid] = bf2f(outs_bf[bt * 128 + tid]);
        else           comb[tid] = ctx[bt * 128 + (tid - 128)];
        __syncthreads();
        float p0 = 0.f, p1 = 0.f, p2 = 0.f, p3 = 0.f;
        if (v < 55) {
            const float* wr = lw + v * 257 + c * 64;
            const float* cb = comb + c * 64;
#pragma unroll
            for (int j = 0; j < 16; ++j) {
                p0 += wr[4*j]   * cb[4*j];
                p1 += wr[4*j+1] * cb[4*j+1];
                p2 += wr[4*j+2] * cb[4*j+2];
                p3 += wr[4*j+3] * cb[4*j+3];
            }
        }
        part[tid] = (p0 + p1) + (p2 + p3);
        __syncthreads();
        if (tid < 55) {
            out[bt * 55 + tid] = fc_b[tid] + part[tid] + part[64 + tid] +
                                 part[128 + tid] + part[192 + tid];
        }
        __syncthreads();
    }
}

// ---------------------------------------------------------------------------
extern "C" void kernel_launch(void* const* d_in, const int* in_sizes, int n_in,
                              void* d_out, int out_size, void* d_ws, size_t ws_size,
                              hipStream_t stream)
{
    const int*   x      = (const int*)d_in[0];
    const float* emb    = (const float*)d_in[1];
    const float* w_ih0  = (const float*)d_in[2];
    const float* b_ih0  = (const float*)d_in[3];
    const float* w_hh0  = (const float*)d_in[4];
    const float* b_hh0  = (const float*)d_in[5];
    const float* w_ih1  = (const float*)d_in[6];
    const float* b_ih1  = (const float*)d_in[7];
    const float* w_hh1  = (const float*)d_in[8];
    const float* b_hh1  = (const float*)d_in[9];
    const float* attn_w = (const float*)d_in[10];
    const float* attn_b = (const float*)d_in[11];
    const float* fc_w   = (const float*)d_in[12];
    const float* fc_b   = (const float*)d_in[13];
    float* out = (float*)d_out;

    char* ws = (char*)d_ws;
    unsigned short* outs_bf = (unsigned short*)(ws);                        // 16 MiB
    unsigned short* outsT   = (unsigned short*)(ws + ((size_t)16 << 20));   // 16 MiB
    unsigned short* q_bf    = (unsigned short*)(ws + ((size_t)32 << 20));   // 16 MiB
    float*          ctx     = (float*)         (ws + ((size_t)48 << 20));   // 32 MiB
    float*          WEp     = (float*)         (ws + ((size_t)80 << 20));   // 28 KiB
    float*          WEg     = (float*)         (ws + ((size_t)81 << 20));   // 32 MiB

    k_we<<<dim3(55), dim3(128), 0, stream>>>(emb, w_ih0, b_ih0, b_hh0, WEp);
    k_weg<<<dim3(32, 64), dim3(256), 0, stream>>>(x, WEp, WEg);
    k_scan5<<<dim3(4), dim3(512), 0, stream>>>(
        WEg, w_hh0, w_ih1, b_ih1, w_hh1, b_hh1, outs_bf);
    k_transpose<<<dim3(8, 64), dim3(256), 0, stream>>>(outs_bf, outsT);
    k_qproj<<<dim3(512), dim3(256), 0, stream>>>(outs_bf, attn_w, attn_b, q_bf);
    k_attn<<<dim3(8, 64), dim3(256), 0, stream>>>(q_bf, outs_bf, outsT, ctx);
    k_fc<<<dim3(1024), dim3(256), 0, stream>>>(outs_bf, ctx, fc_w, fc_b, out);
}